// Round 1
// baseline (566.851 us; speedup 1.0000x reference)
//
#include <hip/hip_runtime.h>

constexpr int MAXDEG = 64;

// ---------------- degree accumulation (dst side, +1 self loop added later) ---
__global__ __launch_bounds__(256) void k_deg(
    const int* __restrict__ dst, const float* __restrict__ ew,
    float* __restrict__ deg, int E)
{
    int e = blockIdx.x * 256 + threadIdx.x;
    if (e < E) atomicAdd(&deg[dst[e]], ew[e]);
}

__global__ __launch_bounds__(256) void k_dinv(
    const float* __restrict__ deg, float* __restrict__ dinv, int n)
{
    int i = blockIdx.x * 256 + threadIdx.x;
    if (i < n) dinv[i] = rsqrtf(deg[i] + 1.0f);   // self-loop weight 1 => deg>0 always
}

// ---------------- build padded-ELL adjacency grouped by dst ------------------
__global__ __launch_bounds__(256) void k_fill(
    const int* __restrict__ src, const int* __restrict__ dst,
    const float* __restrict__ ew, const float* __restrict__ dinv,
    int* __restrict__ cnt, int* __restrict__ ell_src, float* __restrict__ ell_nrm,
    int E)
{
    int e = blockIdx.x * 256 + threadIdx.x;
    if (e >= E) return;
    int s = src[e], d = dst[e];
    int slot = atomicAdd(&cnt[d], 1);
    if (slot < MAXDEG) {
        ell_src[d * MAXDEG + slot] = s;
        ell_nrm[d * MAXDEG + slot] = dinv[s] * ew[e] * dinv[d];
    }
}

// ---------------- C[n][128] = A[n][128] @ W[128][128] ------------------------
// 256 threads: 128 cols x 2 row-groups, 4 rows per thread -> 8 rows/block.
__global__ __launch_bounds__(256) void k_gemm(
    const float* __restrict__ A, const float* __restrict__ W,
    float* __restrict__ C, int n)
{
    const int col  = threadIdx.x & 127;
    const int rs   = threadIdx.x >> 7;
    const int row0 = blockIdx.x * 8 + rs * 4;
    if (row0 >= n) return;
    const int r0 = row0;
    const int r1 = min(row0 + 1, n - 1);
    const int r2 = min(row0 + 2, n - 1);
    const int r3 = min(row0 + 3, n - 1);
    float a0 = 0.f, a1 = 0.f, a2 = 0.f, a3 = 0.f;
    for (int k = 0; k < 128; k += 4) {
        float w0 = W[(k + 0) * 128 + col];
        float w1 = W[(k + 1) * 128 + col];
        float w2 = W[(k + 2) * 128 + col];
        float w3 = W[(k + 3) * 128 + col];
        float4 x0 = *(const float4*)&A[r0 * 128 + k];
        float4 x1 = *(const float4*)&A[r1 * 128 + k];
        float4 x2 = *(const float4*)&A[r2 * 128 + k];
        float4 x3 = *(const float4*)&A[r3 * 128 + k];
        a0 = fmaf(x0.w, w3, fmaf(x0.z, w2, fmaf(x0.y, w1, fmaf(x0.x, w0, a0))));
        a1 = fmaf(x1.w, w3, fmaf(x1.z, w2, fmaf(x1.y, w1, fmaf(x1.x, w0, a1))));
        a2 = fmaf(x2.w, w3, fmaf(x2.z, w2, fmaf(x2.y, w1, fmaf(x2.x, w0, a2))));
        a3 = fmaf(x3.w, w3, fmaf(x3.z, w2, fmaf(x3.y, w1, fmaf(x3.x, w0, a3))));
    }
    C[r0 * 128 + col] = a0;
    if (row0 + 1 < n) C[r1 * 128 + col] = a1;
    if (row0 + 2 < n) C[r2 * 128 + col] = a2;
    if (row0 + 3 < n) C[r3 * 128 + col] = a3;
}

// ---------------- aggregation: out[i] = sum_e norm*h[src] + dinv[i]^2*h[i] + b
// one wave (64 lanes) per dst node, float2 per lane covers 128 features.
template <bool RELU>
__global__ __launch_bounds__(256) void k_agg(
    const float* __restrict__ h, const int* __restrict__ ell_src,
    const float* __restrict__ ell_nrm, const int* __restrict__ cnt,
    const float* __restrict__ dinv, const float* __restrict__ bias,
    float* __restrict__ out, int n)
{
    const int lane = threadIdx.x & 63;
    const int wv   = threadIdx.x >> 6;
    const int i    = blockIdx.x * 4 + wv;
    if (i >= n) return;
    const int f = lane * 2;
    float ax = 0.f, ay = 0.f;
    const int m    = min(cnt[i], MAXDEG);
    const int base = i * MAXDEG;
    for (int j = 0; j < m; ++j) {
        const int   s = ell_src[base + j];   // wave-uniform -> broadcast load
        const float w = ell_nrm[base + j];
        const float2 hv = *(const float2*)&h[s * 128 + f];
        ax = fmaf(w, hv.x, ax);
        ay = fmaf(w, hv.y, ay);
    }
    const float di = dinv[i];
    const float wl = di * di;
    const float2 hs = *(const float2*)&h[i * 128 + f];
    ax = fmaf(wl, hs.x, ax);
    ay = fmaf(wl, hs.y, ay);
    const float2 bb = *(const float2*)&bias[f];
    ax += bb.x; ay += bb.y;
    if (RELU) { ax = fmaxf(ax, 0.f); ay = fmaxf(ay, 0.f); }
    float2 o; o.x = ax; o.y = ay;
    *(float2*)&out[i * 128 + f] = o;
}

// ---------------- mean pool per graph (batch_idx sorted -> binary search) ----
__global__ __launch_bounds__(128) void k_pool(
    const float* __restrict__ h, const int* __restrict__ batch,
    float* __restrict__ gout, int n)
{
    const int gi = blockIdx.x;
    const int t  = threadIdx.x;      // 128 threads = 128 features
    __shared__ int ss, se;
    if (t == 0) {
        int lo = 0, hi = n;
        while (lo < hi) { int m = (lo + hi) >> 1; if (batch[m] < gi) lo = m + 1; else hi = m; }
        ss = lo;
    } else if (t == 1) {
        int lo = 0, hi = n;
        while (lo < hi) { int m = (lo + hi) >> 1; if (batch[m] < gi + 1) lo = m + 1; else hi = m; }
        se = lo;
    }
    __syncthreads();
    float acc = 0.f;
    for (int i = ss; i < se; ++i) acc += h[i * 128 + t];
    float c = (float)(se - ss);
    gout[gi * 128 + t] = acc / fmaxf(c, 1.f);
}

// ---------------- fused head: Linear->ReLU->LayerNorm->Linear ----------------
__global__ __launch_bounds__(128) void k_head(
    const float* __restrict__ g, const float* __restrict__ l1W,
    const float* __restrict__ l1b, const float* __restrict__ gamma,
    const float* __restrict__ beta, const float* __restrict__ l2W,
    const float* __restrict__ l2b, float* __restrict__ out)
{
    const int gi = blockIdx.x;
    const int t  = threadIdx.x;      // 128 threads
    __shared__ float gs[128], zs[128], red[128];
    gs[t] = g[gi * 128 + t];
    __syncthreads();
    float acc = l1b[t];
    for (int k = 0; k < 128; ++k) acc = fmaf(gs[k], l1W[k * 128 + t], acc);
    acc = fmaxf(acc, 0.f);
    // mean
    red[t] = acc; __syncthreads();
    for (int off = 64; off > 0; off >>= 1) {
        if (t < off) red[t] += red[t + off];
        __syncthreads();
    }
    const float mu = red[0] * (1.f / 128.f);
    __syncthreads();
    // var (population)
    const float d = acc - mu;
    red[t] = d * d; __syncthreads();
    for (int off = 64; off > 0; off >>= 1) {
        if (t < off) red[t] += red[t + off];
        __syncthreads();
    }
    const float var = red[0] * (1.f / 128.f);
    const float z = (acc - mu) * rsqrtf(var + 1e-5f) * gamma[t] + beta[t];
    zs[t] = z;
    __syncthreads();
    if (t < 16) {
        float o = l2b[t];
        for (int k = 0; k < 128; ++k) o = fmaf(zs[k], l2W[k * 16 + t], o);
        out[gi * 16 + t] = o;
    }
}

extern "C" void kernel_launch(void* const* d_in, const int* in_sizes, int n_in,
                              void* d_out, int out_size, void* d_ws, size_t ws_size,
                              hipStream_t stream)
{
    const float* x    = (const float*)d_in[0];
    const int*   ei   = (const int*)  d_in[1];
    const float* ew   = (const float*)d_in[2];
    const int*   bidx = (const int*)  d_in[3];
    const float* W1   = (const float*)d_in[4];
    const float* b1   = (const float*)d_in[5];
    const float* W2   = (const float*)d_in[6];
    const float* b2   = (const float*)d_in[7];
    const float* l1W  = (const float*)d_in[8];
    const float* l1b  = (const float*)d_in[9];
    const float* gam  = (const float*)d_in[10];
    const float* bet  = (const float*)d_in[11];
    const float* l2W  = (const float*)d_in[12];
    const float* l2b  = (const float*)d_in[13];
    float* out = (float*)d_out;

    const int E = in_sizes[2];              // edge_weight count
    const int n = in_sizes[3];              // batch_idx count = N nodes
    const int* e_src = ei;                  // edge_index[0]
    const int* e_dst = ei + E;              // edge_index[1]

    char* p = (char*)d_ws;
    auto alloc = [&](size_t bytes) { char* r = p; p += (bytes + 255) & ~(size_t)255; return r; };
    float* h_a   = (float*)alloc((size_t)n * 128 * 4);
    float* h_b   = (float*)alloc((size_t)n * 128 * 4);
    int*   ell_s = (int*)  alloc((size_t)n * MAXDEG * 4);
    float* ell_n = (float*)alloc((size_t)n * MAXDEG * 4);
    float* deg   = (float*)alloc((size_t)n * 4);
    float* dinv  = (float*)alloc((size_t)n * 4);
    int*   cnt   = (int*)  alloc((size_t)n * 4);
    float* gp    = (float*)alloc((size_t)128 * 128 * 4);

    hipMemsetAsync(deg, 0, (size_t)n * 4, stream);
    hipMemsetAsync(cnt, 0, (size_t)n * 4, stream);

    const int gE = (E + 255) / 256;
    const int gN = (n + 255) / 256;

    k_deg <<<gE, 256, 0, stream>>>(e_dst, ew, deg, E);
    k_dinv<<<gN, 256, 0, stream>>>(deg, dinv, n);
    k_fill<<<gE, 256, 0, stream>>>(e_src, e_dst, ew, dinv, cnt, ell_s, ell_n, E);

    k_gemm<<<(n + 7) / 8, 256, 0, stream>>>(x, W1, h_a, n);
    k_agg<true> <<<(n + 3) / 4, 256, 0, stream>>>(h_a, ell_s, ell_n, cnt, dinv, b1, h_b, n);
    k_gemm<<<(n + 7) / 8, 256, 0, stream>>>(h_b, W2, h_a, n);
    k_agg<false><<<(n + 3) / 4, 256, 0, stream>>>(h_a, ell_s, ell_n, cnt, dinv, b2, h_b, n);

    k_pool<<<128, 128, 0, stream>>>(h_b, bidx, gp, n);
    k_head<<<128, 128, 0, stream>>>(gp, l1W, l1b, gam, bet, l2W, l2b, out);
}

// Round 2
// 533.911 us; speedup vs baseline: 1.0617x; 1.0617x over previous
//
#include <hip/hip_runtime.h>

constexpr int MAXDEG = 64;

// ---------------- degree accumulation (dst side, +1 self loop added later) ---
__global__ __launch_bounds__(256) void k_deg(
    const int* __restrict__ dst, const float* __restrict__ ew,
    float* __restrict__ deg, int E)
{
    int e = blockIdx.x * 256 + threadIdx.x;
    if (e < E) atomicAdd(&deg[dst[e]], ew[e]);
}

__global__ __launch_bounds__(256) void k_dinv(
    const float* __restrict__ deg, float* __restrict__ dinv, int n)
{
    int i = blockIdx.x * 256 + threadIdx.x;
    if (i < n) dinv[i] = rsqrtf(deg[i] + 1.0f);   // self-loop weight 1 => deg>0 always
}

// ---------------- build padded-ELL adjacency grouped by dst ------------------
__global__ __launch_bounds__(256) void k_fill(
    const int* __restrict__ src, const int* __restrict__ dst,
    const float* __restrict__ ew, const float* __restrict__ dinv,
    int* __restrict__ cnt, int* __restrict__ ell_src, float* __restrict__ ell_nrm,
    int E)
{
    int e = blockIdx.x * 256 + threadIdx.x;
    if (e >= E) return;
    int s = src[e], d = dst[e];
    int slot = atomicAdd(&cnt[d], 1);
    if (slot < MAXDEG) {
        ell_src[d * MAXDEG + slot] = s;
        ell_nrm[d * MAXDEG + slot] = dinv[s] * ew[e] * dinv[d];
    }
}

// ---------------- C[n][128] = A[n][128] @ W[128][128] ------------------------
// W staged in LDS (64 KB, 2 blocks/CU). 512 blocks own contiguous row ranges.
// 256 threads = 128 cols x 2 row-groups; 8 rows per thread -> 16 rows/chunk.
// LDS read Ws[k*128+col]: 2 lanes/bank = conflict-free. A loads wave-broadcast.
__global__ __launch_bounds__(256, 2) void k_gemm(
    const float* __restrict__ A, const float* __restrict__ W,
    float* __restrict__ C, int n, int rpb)
{
    __shared__ float Ws[128 * 128];
    {
        const float4* __restrict__ Wv = (const float4*)W;
        float4* Sv = (float4*)Ws;
        #pragma unroll
        for (int idx = 0; idx < 16; ++idx)
            Sv[threadIdx.x + idx * 256] = Wv[threadIdx.x + idx * 256];
    }
    __syncthreads();

    const int col = threadIdx.x & 127;
    const int rg  = threadIdx.x >> 7;        // 0..1
    const int blockStart = blockIdx.x * rpb;
    const int rowEnd = min(blockStart + rpb, n);

    for (int row0 = blockStart + rg * 8; row0 < rowEnd; row0 += 16) {
        const float* ap[8];
        #pragma unroll
        for (int i = 0; i < 8; ++i)
            ap[i] = A + (size_t)min(row0 + i, n - 1) * 128;

        float acc[8];
        #pragma unroll
        for (int i = 0; i < 8; ++i) acc[i] = 0.f;

        #pragma unroll 2
        for (int k = 0; k < 128; k += 4) {
            const float w0 = Ws[(k + 0) * 128 + col];
            const float w1 = Ws[(k + 1) * 128 + col];
            const float w2 = Ws[(k + 2) * 128 + col];
            const float w3 = Ws[(k + 3) * 128 + col];
            #pragma unroll
            for (int i = 0; i < 8; ++i) {
                const float4 xv = *(const float4*)&ap[i][k];
                acc[i] = fmaf(xv.w, w3, fmaf(xv.z, w2,
                          fmaf(xv.y, w1, fmaf(xv.x, w0, acc[i]))));
            }
        }

        #pragma unroll
        for (int i = 0; i < 8; ++i) {
            const int r = row0 + i;
            if (r < rowEnd) C[(size_t)r * 128 + col] = acc[i];
        }
    }
}

// ---------------- aggregation: out[i] = sum_e norm*h[src] + dinv[i]^2*h[i] + b
// one wave (64 lanes) per dst node, float2 per lane covers 128 features.
template <bool RELU>
__global__ __launch_bounds__(256) void k_agg(
    const float* __restrict__ h, const int* __restrict__ ell_src,
    const float* __restrict__ ell_nrm, const int* __restrict__ cnt,
    const float* __restrict__ dinv, const float* __restrict__ bias,
    float* __restrict__ out, int n)
{
    const int lane = threadIdx.x & 63;
    const int wv   = threadIdx.x >> 6;
    const int i    = blockIdx.x * 4 + wv;
    if (i >= n) return;
    const int f = lane * 2;
    float ax = 0.f, ay = 0.f;
    const int m    = min(cnt[i], MAXDEG);
    const int base = i * MAXDEG;
    for (int j = 0; j < m; ++j) {
        const int   s = ell_src[base + j];   // wave-uniform -> broadcast load
        const float w = ell_nrm[base + j];
        const float2 hv = *(const float2*)&h[s * 128 + f];
        ax = fmaf(w, hv.x, ax);
        ay = fmaf(w, hv.y, ay);
    }
    const float di = dinv[i];
    const float wl = di * di;
    const float2 hs = *(const float2*)&h[i * 128 + f];
    ax = fmaf(wl, hs.x, ax);
    ay = fmaf(wl, hs.y, ay);
    const float2 bb = *(const float2*)&bias[f];
    ax += bb.x; ay += bb.y;
    if (RELU) { ax = fmaxf(ax, 0.f); ay = fmaxf(ay, 0.f); }
    float2 o; o.x = ax; o.y = ay;
    *(float2*)&out[i * 128 + f] = o;
}

// ---------------- mean pool per graph (batch_idx sorted -> binary search) ----
__global__ __launch_bounds__(128) void k_pool(
    const float* __restrict__ h, const int* __restrict__ batch,
    float* __restrict__ gout, int n)
{
    const int gi = blockIdx.x;
    const int t  = threadIdx.x;      // 128 threads = 128 features
    __shared__ int ss, se;
    if (t == 0) {
        int lo = 0, hi = n;
        while (lo < hi) { int m = (lo + hi) >> 1; if (batch[m] < gi) lo = m + 1; else hi = m; }
        ss = lo;
    } else if (t == 1) {
        int lo = 0, hi = n;
        while (lo < hi) { int m = (lo + hi) >> 1; if (batch[m] < gi + 1) lo = m + 1; else hi = m; }
        se = lo;
    }
    __syncthreads();
    float acc = 0.f;
    for (int i = ss; i < se; ++i) acc += h[i * 128 + t];
    float c = (float)(se - ss);
    gout[gi * 128 + t] = acc / fmaxf(c, 1.f);
}

// ---------------- fused head: Linear->ReLU->LayerNorm->Linear ----------------
__global__ __launch_bounds__(128) void k_head(
    const float* __restrict__ g, const float* __restrict__ l1W,
    const float* __restrict__ l1b, const float* __restrict__ gamma,
    const float* __restrict__ beta, const float* __restrict__ l2W,
    const float* __restrict__ l2b, float* __restrict__ out)
{
    const int gi = blockIdx.x;
    const int t  = threadIdx.x;      // 128 threads
    __shared__ float gs[128], zs[128], red[128];
    gs[t] = g[gi * 128 + t];
    __syncthreads();
    float acc = l1b[t];
    for (int k = 0; k < 128; ++k) acc = fmaf(gs[k], l1W[k * 128 + t], acc);
    acc = fmaxf(acc, 0.f);
    // mean
    red[t] = acc; __syncthreads();
    for (int off = 64; off > 0; off >>= 1) {
        if (t < off) red[t] += red[t + off];
        __syncthreads();
    }
    const float mu = red[0] * (1.f / 128.f);
    __syncthreads();
    // var (population)
    const float d = acc - mu;
    red[t] = d * d; __syncthreads();
    for (int off = 64; off > 0; off >>= 1) {
        if (t < off) red[t] += red[t + off];
        __syncthreads();
    }
    const float var = red[0] * (1.f / 128.f);
    const float z = (acc - mu) * rsqrtf(var + 1e-5f) * gamma[t] + beta[t];
    zs[t] = z;
    __syncthreads();
    if (t < 16) {
        float o = l2b[t];
        for (int k = 0; k < 128; ++k) o = fmaf(zs[k], l2W[k * 16 + t], o);
        out[gi * 16 + t] = o;
    }
}

extern "C" void kernel_launch(void* const* d_in, const int* in_sizes, int n_in,
                              void* d_out, int out_size, void* d_ws, size_t ws_size,
                              hipStream_t stream)
{
    const float* x    = (const float*)d_in[0];
    const int*   ei   = (const int*)  d_in[1];
    const float* ew   = (const float*)d_in[2];
    const int*   bidx = (const int*)  d_in[3];
    const float* W1   = (const float*)d_in[4];
    const float* b1   = (const float*)d_in[5];
    const float* W2   = (const float*)d_in[6];
    const float* b2   = (const float*)d_in[7];
    const float* l1W  = (const float*)d_in[8];
    const float* l1b  = (const float*)d_in[9];
    const float* gam  = (const float*)d_in[10];
    const float* bet  = (const float*)d_in[11];
    const float* l2W  = (const float*)d_in[12];
    const float* l2b  = (const float*)d_in[13];
    float* out = (float*)d_out;

    const int E = in_sizes[2];              // edge_weight count
    const int n = in_sizes[3];              // batch_idx count = N nodes
    const int* e_src = ei;                  // edge_index[0]
    const int* e_dst = ei + E;              // edge_index[1]

    char* p = (char*)d_ws;
    auto alloc = [&](size_t bytes) { char* r = p; p += (bytes + 255) & ~(size_t)255; return r; };
    float* h_a   = (float*)alloc((size_t)n * 128 * 4);
    float* h_b   = (float*)alloc((size_t)n * 128 * 4);
    int*   ell_s = (int*)  alloc((size_t)n * MAXDEG * 4);
    float* ell_n = (float*)alloc((size_t)n * MAXDEG * 4);
    float* deg   = (float*)alloc((size_t)n * 4);
    float* dinv  = (float*)alloc((size_t)n * 4);
    int*   cnt   = (int*)  alloc((size_t)n * 4);
    float* gp    = (float*)alloc((size_t)128 * 128 * 4);

    hipMemsetAsync(deg, 0, (size_t)n * 4, stream);
    hipMemsetAsync(cnt, 0, (size_t)n * 4, stream);

    const int gE = (E + 255) / 256;
    const int gN = (n + 255) / 256;

    k_deg <<<gE, 256, 0, stream>>>(e_dst, ew, deg, E);
    k_dinv<<<gN, 256, 0, stream>>>(deg, dinv, n);
    k_fill<<<gE, 256, 0, stream>>>(e_src, e_dst, ew, dinv, cnt, ell_s, ell_n, E);

    const int NB  = 512;
    const int rpb = (n + NB - 1) / NB;
    k_gemm<<<NB, 256, 0, stream>>>(x, W1, h_a, n, rpb);
    k_agg<true> <<<(n + 3) / 4, 256, 0, stream>>>(h_a, ell_s, ell_n, cnt, dinv, b1, h_b, n);
    k_gemm<<<NB, 256, 0, stream>>>(h_b, W2, h_a, n, rpb);
    k_agg<false><<<(n + 3) / 4, 256, 0, stream>>>(h_a, ell_s, ell_n, cnt, dinv, b2, h_b, n);

    k_pool<<<128, 128, 0, stream>>>(h_b, bidx, gp, n);
    k_head<<<128, 128, 0, stream>>>(gp, l1W, l1b, gam, bet, l2W, l2b, out);
}

// Round 3
// 410.410 us; speedup vs baseline: 1.3812x; 1.3009x over previous
//
#include <hip/hip_runtime.h>

constexpr int MAXDEG = 64;

// ---------------- degree accumulation (dst side, +1 self loop added later) ---
__global__ __launch_bounds__(256) void k_deg(
    const int* __restrict__ dst, const float* __restrict__ ew,
    float* __restrict__ deg, int E)
{
    int e = blockIdx.x * 256 + threadIdx.x;
    if (e < E) atomicAdd(&deg[dst[e]], ew[e]);
}

__global__ __launch_bounds__(256) void k_dinv(
    const float* __restrict__ deg, float* __restrict__ dinv, int n)
{
    int i = blockIdx.x * 256 + threadIdx.x;
    if (i < n) dinv[i] = rsqrtf(deg[i] + 1.0f);   // self-loop weight 1 => deg>0 always
}

// ---------------- build padded-ELL adjacency grouped by dst ------------------
__global__ __launch_bounds__(256) void k_fill(
    const int* __restrict__ src, const int* __restrict__ dst,
    const float* __restrict__ ew, const float* __restrict__ dinv,
    int* __restrict__ cnt, int* __restrict__ ell_src, float* __restrict__ ell_nrm,
    int E)
{
    int e = blockIdx.x * 256 + threadIdx.x;
    if (e >= E) return;
    int s = src[e], d = dst[e];
    int slot = atomicAdd(&cnt[d], 1);
    if (slot < MAXDEG) {
        ell_src[d * MAXDEG + slot] = s;
        ell_nrm[d * MAXDEG + slot] = dinv[s] * ew[e] * dinv[d];
    }
}

// ---------------- C[n][128] = A[n][128] @ W[128][128] ------------------------
// Register-tiled: thread = 8 rows x 4 cols (32 acc). W f32 staged in LDS.
// Per 4-k step: 4 ds_read_b128 + 8 global dwordx4 + 128 FMA (89% FMA density).
// 782 blocks x 64 rows: one full iteration per block, no partial-tile waste.
__global__ __launch_bounds__(256, 2) void k_gemm(
    const float* __restrict__ A, const float* __restrict__ W,
    float* __restrict__ C, int n)
{
    __shared__ float Ws[128 * 128];
    {
        const float4* __restrict__ Wv = (const float4*)W;
        float4* Sv = (float4*)Ws;
        #pragma unroll
        for (int i = 0; i < 16; ++i)
            Sv[threadIdx.x + i * 256] = Wv[threadIdx.x + i * 256];
    }
    __syncthreads();

    const int col0 = (threadIdx.x & 31) * 4;   // 32 threads cover 128 cols
    const int rg   = threadIdx.x >> 5;         // 0..7 row-groups of 8
    const int row0 = blockIdx.x * 64 + rg * 8;
    const int rowEnd = min(blockIdx.x * 64 + 64, n);

    const float* ap[8];
    #pragma unroll
    for (int r = 0; r < 8; ++r)
        ap[r] = A + (size_t)min(row0 + r, n - 1) * 128;

    float acc[8][4];
    #pragma unroll
    for (int r = 0; r < 8; ++r)
        #pragma unroll
        for (int c = 0; c < 4; ++c) acc[r][c] = 0.f;

    for (int k = 0; k < 128; k += 4) {
        float4 w0 = *(const float4*)&Ws[(k + 0) * 128 + col0];
        float4 w1 = *(const float4*)&Ws[(k + 1) * 128 + col0];
        float4 w2 = *(const float4*)&Ws[(k + 2) * 128 + col0];
        float4 w3 = *(const float4*)&Ws[(k + 3) * 128 + col0];
        #pragma unroll
        for (int r = 0; r < 8; ++r) {
            const float4 av = *(const float4*)&ap[r][k];
            acc[r][0] = fmaf(av.x, w0.x, acc[r][0]);
            acc[r][1] = fmaf(av.x, w0.y, acc[r][1]);
            acc[r][2] = fmaf(av.x, w0.z, acc[r][2]);
            acc[r][3] = fmaf(av.x, w0.w, acc[r][3]);
            acc[r][0] = fmaf(av.y, w1.x, acc[r][0]);
            acc[r][1] = fmaf(av.y, w1.y, acc[r][1]);
            acc[r][2] = fmaf(av.y, w1.z, acc[r][2]);
            acc[r][3] = fmaf(av.y, w1.w, acc[r][3]);
            acc[r][0] = fmaf(av.z, w2.x, acc[r][0]);
            acc[r][1] = fmaf(av.z, w2.y, acc[r][1]);
            acc[r][2] = fmaf(av.z, w2.z, acc[r][2]);
            acc[r][3] = fmaf(av.z, w2.w, acc[r][3]);
            acc[r][0] = fmaf(av.w, w3.x, acc[r][0]);
            acc[r][1] = fmaf(av.w, w3.y, acc[r][1]);
            acc[r][2] = fmaf(av.w, w3.z, acc[r][2]);
            acc[r][3] = fmaf(av.w, w3.w, acc[r][3]);
        }
    }

    #pragma unroll
    for (int r = 0; r < 8; ++r) {
        const int row = row0 + r;
        if (row < rowEnd) {
            float4 o; o.x = acc[r][0]; o.y = acc[r][1]; o.z = acc[r][2]; o.w = acc[r][3];
            *(float4*)&C[(size_t)row * 128 + col0] = o;
        }
    }
}

// ---------------- aggregation: out[i] = sum_e norm*h[src] + dinv[i]^2*h[i] + b
// one wave (64 lanes) per dst node, float2 per lane covers 128 features.
template <bool RELU>
__global__ __launch_bounds__(256) void k_agg(
    const float* __restrict__ h, const int* __restrict__ ell_src,
    const float* __restrict__ ell_nrm, const int* __restrict__ cnt,
    const float* __restrict__ dinv, const float* __restrict__ bias,
    float* __restrict__ out, int n)
{
    const int lane = threadIdx.x & 63;
    const int wv   = threadIdx.x >> 6;
    const int i    = blockIdx.x * 4 + wv;
    if (i >= n) return;
    const int f = lane * 2;
    float ax = 0.f, ay = 0.f;
    const int m    = min(cnt[i], MAXDEG);
    const int base = i * MAXDEG;
    for (int j = 0; j < m; ++j) {
        const int   s = ell_src[base + j];   // wave-uniform -> broadcast load
        const float w = ell_nrm[base + j];
        const float2 hv = *(const float2*)&h[s * 128 + f];
        ax = fmaf(w, hv.x, ax);
        ay = fmaf(w, hv.y, ay);
    }
    const float di = dinv[i];
    const float wl = di * di;
    const float2 hs = *(const float2*)&h[i * 128 + f];
    ax = fmaf(wl, hs.x, ax);
    ay = fmaf(wl, hs.y, ay);
    const float2 bb = *(const float2*)&bias[f];
    ax += bb.x; ay += bb.y;
    if (RELU) { ax = fmaxf(ax, 0.f); ay = fmaxf(ay, 0.f); }
    float2 o; o.x = ax; o.y = ay;
    *(float2*)&out[i * 128 + f] = o;
}

// ---------------- mean pool per graph (batch_idx sorted -> binary search) ----
__global__ __launch_bounds__(128) void k_pool(
    const float* __restrict__ h, const int* __restrict__ batch,
    float* __restrict__ gout, int n)
{
    const int gi = blockIdx.x;
    const int t  = threadIdx.x;      // 128 threads = 128 features
    __shared__ int ss, se;
    if (t == 0) {
        int lo = 0, hi = n;
        while (lo < hi) { int m = (lo + hi) >> 1; if (batch[m] < gi) lo = m + 1; else hi = m; }
        ss = lo;
    } else if (t == 1) {
        int lo = 0, hi = n;
        while (lo < hi) { int m = (lo + hi) >> 1; if (batch[m] < gi + 1) lo = m + 1; else hi = m; }
        se = lo;
    }
    __syncthreads();
    float acc = 0.f;
    for (int i = ss; i < se; ++i) acc += h[i * 128 + t];
    float c = (float)(se - ss);
    gout[gi * 128 + t] = acc / fmaxf(c, 1.f);
}

// ---------------- fused head: Linear->ReLU->LayerNorm->Linear ----------------
__global__ __launch_bounds__(128) void k_head(
    const float* __restrict__ g, const float* __restrict__ l1W,
    const float* __restrict__ l1b, const float* __restrict__ gamma,
    const float* __restrict__ beta, const float* __restrict__ l2W,
    const float* __restrict__ l2b, float* __restrict__ out)
{
    const int gi = blockIdx.x;
    const int t  = threadIdx.x;      // 128 threads
    __shared__ float gs[128], zs[128], red[128];
    gs[t] = g[gi * 128 + t];
    __syncthreads();
    float acc = l1b[t];
    for (int k = 0; k < 128; ++k) acc = fmaf(gs[k], l1W[k * 128 + t], acc);
    acc = fmaxf(acc, 0.f);
    // mean
    red[t] = acc; __syncthreads();
    for (int off = 64; off > 0; off >>= 1) {
        if (t < off) red[t] += red[t + off];
        __syncthreads();
    }
    const float mu = red[0] * (1.f / 128.f);
    __syncthreads();
    // var (population)
    const float d = acc - mu;
    red[t] = d * d; __syncthreads();
    for (int off = 64; off > 0; off >>= 1) {
        if (t < off) red[t] += red[t + off];
        __syncthreads();
    }
    const float var = red[0] * (1.f / 128.f);
    const float z = (acc - mu) * rsqrtf(var + 1e-5f) * gamma[t] + beta[t];
    zs[t] = z;
    __syncthreads();
    if (t < 16) {
        float o = l2b[t];
        for (int k = 0; k < 128; ++k) o = fmaf(zs[k], l2W[k * 16 + t], o);
        out[gi * 16 + t] = o;
    }
}

extern "C" void kernel_launch(void* const* d_in, const int* in_sizes, int n_in,
                              void* d_out, int out_size, void* d_ws, size_t ws_size,
                              hipStream_t stream)
{
    const float* x    = (const float*)d_in[0];
    const int*   ei   = (const int*)  d_in[1];
    const float* ew   = (const float*)d_in[2];
    const int*   bidx = (const int*)  d_in[3];
    const float* W1   = (const float*)d_in[4];
    const float* b1   = (const float*)d_in[5];
    const float* W2   = (const float*)d_in[6];
    const float* b2   = (const float*)d_in[7];
    const float* l1W  = (const float*)d_in[8];
    const float* l1b  = (const float*)d_in[9];
    const float* gam  = (const float*)d_in[10];
    const float* bet  = (const float*)d_in[11];
    const float* l2W  = (const float*)d_in[12];
    const float* l2b  = (const float*)d_in[13];
    float* out = (float*)d_out;

    const int E = in_sizes[2];              // edge_weight count
    const int n = in_sizes[3];              // batch_idx count = N nodes
    const int* e_src = ei;                  // edge_index[0]
    const int* e_dst = ei + E;              // edge_index[1]

    char* p = (char*)d_ws;
    auto alloc = [&](size_t bytes) { char* r = p; p += (bytes + 255) & ~(size_t)255; return r; };
    float* h_a   = (float*)alloc((size_t)n * 128 * 4);
    float* h_b   = (float*)alloc((size_t)n * 128 * 4);
    int*   ell_s = (int*)  alloc((size_t)n * MAXDEG * 4);
    float* ell_n = (float*)alloc((size_t)n * MAXDEG * 4);
    float* deg   = (float*)alloc((size_t)n * 4);
    float* dinv  = (float*)alloc((size_t)n * 4);
    int*   cnt   = (int*)  alloc((size_t)n * 4);
    float* gp    = (float*)alloc((size_t)128 * 128 * 4);

    hipMemsetAsync(deg, 0, (size_t)n * 4, stream);
    hipMemsetAsync(cnt, 0, (size_t)n * 4, stream);

    const int gE = (E + 255) / 256;
    const int gN = (n + 255) / 256;

    k_deg <<<gE, 256, 0, stream>>>(e_dst, ew, deg, E);
    k_dinv<<<gN, 256, 0, stream>>>(deg, dinv, n);
    k_fill<<<gE, 256, 0, stream>>>(e_src, e_dst, ew, dinv, cnt, ell_s, ell_n, E);

    const int NB = (n + 63) / 64;           // 782: one 64-row tile per block
    k_gemm<<<NB, 256, 0, stream>>>(x, W1, h_a, n);
    k_agg<true> <<<(n + 3) / 4, 256, 0, stream>>>(h_a, ell_s, ell_n, cnt, dinv, b1, h_b, n);
    k_gemm<<<NB, 256, 0, stream>>>(h_b, W2, h_a, n);
    k_agg<false><<<(n + 3) / 4, 256, 0, stream>>>(h_a, ell_s, ell_n, cnt, dinv, b2, h_b, n);

    k_pool<<<128, 128, 0, stream>>>(h_b, bidx, gp, n);
    k_head<<<128, 128, 0, stream>>>(gp, l1W, l1b, gam, bet, l2W, l2b, out);
}

// Round 4
// 315.804 us; speedup vs baseline: 1.7949x; 1.2996x over previous
//
#include <hip/hip_runtime.h>

constexpr int MAXDEG = 64;

// ---------------- degree accumulation (dst side, +1 self loop added later) ---
__global__ __launch_bounds__(256) void k_deg(
    const int* __restrict__ dst, const float* __restrict__ ew,
    float* __restrict__ deg, int E)
{
    int e = blockIdx.x * 256 + threadIdx.x;
    if (e < E) atomicAdd(&deg[dst[e]], ew[e]);
}

__global__ __launch_bounds__(256) void k_dinv(
    const float* __restrict__ deg, float* __restrict__ dinv, int n)
{
    int i = blockIdx.x * 256 + threadIdx.x;
    if (i < n) dinv[i] = rsqrtf(deg[i] + 1.0f);   // self-loop weight 1 => deg>0 always
}

// ---------------- build padded-ELL adjacency grouped by dst ------------------
__global__ __launch_bounds__(256) void k_fill(
    const int* __restrict__ src, const int* __restrict__ dst,
    const float* __restrict__ ew, const float* __restrict__ dinv,
    int* __restrict__ cnt, int* __restrict__ ell_src, float* __restrict__ ell_nrm,
    int E)
{
    int e = blockIdx.x * 256 + threadIdx.x;
    if (e >= E) return;
    int s = src[e], d = dst[e];
    int slot = atomicAdd(&cnt[d], 1);
    if (slot < MAXDEG) {
        ell_src[d * MAXDEG + slot] = s;
        ell_nrm[d * MAXDEG + slot] = dinv[s] * ew[e] * dinv[d];
    }
}

// ---------------- C[n][128] = A[n][128] @ W[128][128] ------------------------
// Register-tiled: thread = 8 rows x 4 cols (32 acc). W f32 staged in LDS.
__global__ __launch_bounds__(256, 2) void k_gemm(
    const float* __restrict__ A, const float* __restrict__ W,
    float* __restrict__ C, int n)
{
    __shared__ float Ws[128 * 128];
    {
        const float4* __restrict__ Wv = (const float4*)W;
        float4* Sv = (float4*)Ws;
        #pragma unroll
        for (int i = 0; i < 16; ++i)
            Sv[threadIdx.x + i * 256] = Wv[threadIdx.x + i * 256];
    }
    __syncthreads();

    const int col0 = (threadIdx.x & 31) * 4;   // 32 threads cover 128 cols
    const int rg   = threadIdx.x >> 5;         // 0..7 row-groups of 8
    const int row0 = blockIdx.x * 64 + rg * 8;
    const int rowEnd = min(blockIdx.x * 64 + 64, n);

    const float* ap[8];
    #pragma unroll
    for (int r = 0; r < 8; ++r)
        ap[r] = A + (size_t)min(row0 + r, n - 1) * 128;

    float acc[8][4];
    #pragma unroll
    for (int r = 0; r < 8; ++r)
        #pragma unroll
        for (int c = 0; c < 4; ++c) acc[r][c] = 0.f;

    for (int k = 0; k < 128; k += 4) {
        float4 w0 = *(const float4*)&Ws[(k + 0) * 128 + col0];
        float4 w1 = *(const float4*)&Ws[(k + 1) * 128 + col0];
        float4 w2 = *(const float4*)&Ws[(k + 2) * 128 + col0];
        float4 w3 = *(const float4*)&Ws[(k + 3) * 128 + col0];
        #pragma unroll
        for (int r = 0; r < 8; ++r) {
            const float4 av = *(const float4*)&ap[r][k];
            acc[r][0] = fmaf(av.x, w0.x, acc[r][0]);
            acc[r][1] = fmaf(av.x, w0.y, acc[r][1]);
            acc[r][2] = fmaf(av.x, w0.z, acc[r][2]);
            acc[r][3] = fmaf(av.x, w0.w, acc[r][3]);
            acc[r][0] = fmaf(av.y, w1.x, acc[r][0]);
            acc[r][1] = fmaf(av.y, w1.y, acc[r][1]);
            acc[r][2] = fmaf(av.y, w1.z, acc[r][2]);
            acc[r][3] = fmaf(av.y, w1.w, acc[r][3]);
            acc[r][0] = fmaf(av.z, w2.x, acc[r][0]);
            acc[r][1] = fmaf(av.z, w2.y, acc[r][1]);
            acc[r][2] = fmaf(av.z, w2.z, acc[r][2]);
            acc[r][3] = fmaf(av.z, w2.w, acc[r][3]);
            acc[r][0] = fmaf(av.w, w3.x, acc[r][0]);
            acc[r][1] = fmaf(av.w, w3.y, acc[r][1]);
            acc[r][2] = fmaf(av.w, w3.z, acc[r][2]);
            acc[r][3] = fmaf(av.w, w3.w, acc[r][3]);
        }
    }

    #pragma unroll
    for (int r = 0; r < 8; ++r) {
        const int row = row0 + r;
        if (row < rowEnd) {
            float4 o; o.x = acc[r][0]; o.y = acc[r][1]; o.z = acc[r][2]; o.w = acc[r][3];
            *(float4*)&C[(size_t)row * 128 + col0] = o;
        }
    }
}

// ---------------- aggregation: out[i] = sum_e norm*h[src] + dinv[i]^2*h[i] + b
// one wave (64 lanes) per dst node, float2 per lane covers 128 features.
template <bool RELU>
__global__ __launch_bounds__(256) void k_agg(
    const float* __restrict__ h, const int* __restrict__ ell_src,
    const float* __restrict__ ell_nrm, const int* __restrict__ cnt,
    const float* __restrict__ dinv, const float* __restrict__ bias,
    float* __restrict__ out, int n)
{
    const int lane = threadIdx.x & 63;
    const int wv   = threadIdx.x >> 6;
    const int i    = blockIdx.x * 4 + wv;
    if (i >= n) return;
    const int f = lane * 2;
    float ax = 0.f, ay = 0.f;
    const int m    = min(cnt[i], MAXDEG);
    const int base = i * MAXDEG;
    for (int j = 0; j < m; ++j) {
        const int   s = ell_src[base + j];   // wave-uniform -> broadcast load
        const float w = ell_nrm[base + j];
        const float2 hv = *(const float2*)&h[s * 128 + f];
        ax = fmaf(w, hv.x, ax);
        ay = fmaf(w, hv.y, ay);
    }
    const float di = dinv[i];
    const float wl = di * di;
    const float2 hs = *(const float2*)&h[i * 128 + f];
    ax = fmaf(wl, hs.x, ax);
    ay = fmaf(wl, hs.y, ay);
    const float2 bb = *(const float2*)&bias[f];
    ax += bb.x; ay += bb.y;
    if (RELU) { ax = fmaxf(ax, 0.f); ay = fmaxf(ay, 0.f); }
    float2 o; o.x = ax; o.y = ay;
    *(float2*)&out[i * 128 + f] = o;
}

// ---------------- mean pool per graph: 1024 threads = 16 waves --------------
// wave j handles rows ss+j, ss+j+16, ...; lane covers 128 feats via float2.
// LDS reduce across the 16 waves. Deterministic (fixed order, no atomics).
__global__ __launch_bounds__(1024) void k_pool(
    const float* __restrict__ h, const int* __restrict__ batch,
    float* __restrict__ gout, int n)
{
    const int gi   = blockIdx.x;
    const int lane = threadIdx.x & 63;
    const int wv   = threadIdx.x >> 6;        // 0..15
    __shared__ int sse[2];
    __shared__ float red[16 * 128];
    if (threadIdx.x < 2) {
        const int target = gi + (int)threadIdx.x;
        int lo = 0, hi = n;
        while (lo < hi) { int m = (lo + hi) >> 1; if (batch[m] < target) lo = m + 1; else hi = m; }
        sse[threadIdx.x] = lo;
    }
    __syncthreads();
    const int ss = sse[0], se = sse[1];
    const int f = lane * 2;
    float ax = 0.f, ay = 0.f;
    for (int i = ss + wv; i < se; i += 16) {
        const float2 hv = *(const float2*)&h[(size_t)i * 128 + f];
        ax += hv.x; ay += hv.y;
    }
    red[wv * 128 + f]     = ax;
    red[wv * 128 + f + 1] = ay;
    __syncthreads();
    if (threadIdx.x < 128) {
        const int t = threadIdx.x;
        float acc = 0.f;
        #pragma unroll
        for (int j = 0; j < 16; ++j) acc += red[j * 128 + t];
        const float c = (float)(se - ss);
        gout[gi * 128 + t] = acc / fmaxf(c, 1.f);
    }
}

// ---------------- fused head: Linear->ReLU->LayerNorm->Linear ----------------
__global__ __launch_bounds__(128) void k_head(
    const float* __restrict__ g, const float* __restrict__ l1W,
    const float* __restrict__ l1b, const float* __restrict__ gamma,
    const float* __restrict__ beta, const float* __restrict__ l2W,
    const float* __restrict__ l2b, float* __restrict__ out)
{
    const int gi = blockIdx.x;
    const int t  = threadIdx.x;      // 128 threads
    __shared__ float gs[128], zs[128], red[128];
    gs[t] = g[gi * 128 + t];
    __syncthreads();
    float acc = l1b[t];
    for (int k = 0; k < 128; ++k) acc = fmaf(gs[k], l1W[k * 128 + t], acc);
    acc = fmaxf(acc, 0.f);
    // mean
    red[t] = acc; __syncthreads();
    for (int off = 64; off > 0; off >>= 1) {
        if (t < off) red[t] += red[t + off];
        __syncthreads();
    }
    const float mu = red[0] * (1.f / 128.f);
    __syncthreads();
    // var (population)
    const float d = acc - mu;
    red[t] = d * d; __syncthreads();
    for (int off = 64; off > 0; off >>= 1) {
        if (t < off) red[t] += red[t + off];
        __syncthreads();
    }
    const float var = red[0] * (1.f / 128.f);
    const float z = (acc - mu) * rsqrtf(var + 1e-5f) * gamma[t] + beta[t];
    zs[t] = z;
    __syncthreads();
    if (t < 16) {
        float o = l2b[t];
        for (int k = 0; k < 128; ++k) o = fmaf(zs[k], l2W[k * 16 + t], o);
        out[gi * 16 + t] = o;
    }
}

extern "C" void kernel_launch(void* const* d_in, const int* in_sizes, int n_in,
                              void* d_out, int out_size, void* d_ws, size_t ws_size,
                              hipStream_t stream)
{
    const float* x    = (const float*)d_in[0];
    const int*   ei   = (const int*)  d_in[1];
    const float* ew   = (const float*)d_in[2];
    const int*   bidx = (const int*)  d_in[3];
    const float* W1   = (const float*)d_in[4];
    const float* b1   = (const float*)d_in[5];
    const float* W2   = (const float*)d_in[6];
    const float* b2   = (const float*)d_in[7];
    const float* l1W  = (const float*)d_in[8];
    const float* l1b  = (const float*)d_in[9];
    const float* gam  = (const float*)d_in[10];
    const float* bet  = (const float*)d_in[11];
    const float* l2W  = (const float*)d_in[12];
    const float* l2b  = (const float*)d_in[13];
    float* out = (float*)d_out;

    const int E = in_sizes[2];              // edge_weight count
    const int n = in_sizes[3];              // batch_idx count = N nodes
    const int* e_src = ei;                  // edge_index[0]
    const int* e_dst = ei + E;              // edge_index[1]

    char* p = (char*)d_ws;
    auto alloc = [&](size_t bytes) { char* r = p; p += (bytes + 255) & ~(size_t)255; return r; };
    float* h_a   = (float*)alloc((size_t)n * 128 * 4);
    float* h_b   = (float*)alloc((size_t)n * 128 * 4);
    int*   ell_s = (int*)  alloc((size_t)n * MAXDEG * 4);
    float* ell_n = (float*)alloc((size_t)n * MAXDEG * 4);
    float* deg   = (float*)alloc((size_t)n * 4);
    float* dinv  = (float*)alloc((size_t)n * 4);
    int*   cnt   = (int*)  alloc((size_t)n * 4);
    float* gp    = (float*)alloc((size_t)128 * 128 * 4);

    hipMemsetAsync(deg, 0, (size_t)n * 4, stream);
    hipMemsetAsync(cnt, 0, (size_t)n * 4, stream);

    const int gE = (E + 255) / 256;
    const int gN = (n + 255) / 256;

    k_deg <<<gE, 256, 0, stream>>>(e_dst, ew, deg, E);
    k_dinv<<<gN, 256, 0, stream>>>(deg, dinv, n);
    k_fill<<<gE, 256, 0, stream>>>(e_src, e_dst, ew, dinv, cnt, ell_s, ell_n, E);

    const int NB = (n + 63) / 64;           // one 64-row tile per block
    k_gemm<<<NB, 256, 0, stream>>>(x, W1, h_a, n);
    k_agg<true> <<<(n + 3) / 4, 256, 0, stream>>>(h_a, ell_s, ell_n, cnt, dinv, b1, h_b, n);
    k_gemm<<<NB, 256, 0, stream>>>(h_b, W2, h_a, n);
    k_agg<false><<<(n + 3) / 4, 256, 0, stream>>>(h_a, ell_s, ell_n, cnt, dinv, b2, h_b, n);

    k_pool<<<128, 1024, 0, stream>>>(h_b, bidx, gp, n);
    k_head<<<128, 128, 0, stream>>>(gp, l1W, l1b, gam, bet, l2W, l2b, out);
}

// Round 5
// 276.652 us; speedup vs baseline: 2.0490x; 1.1415x over previous
//
#include <hip/hip_runtime.h>

constexpr int MAXDEG = 64;

// ---------------- degree accumulation (dst side, +1 self loop added later) ---
__global__ __launch_bounds__(256) void k_deg(
    const int* __restrict__ dst, const float* __restrict__ ew,
    float* __restrict__ deg, int E)
{
    int e = blockIdx.x * 256 + threadIdx.x;
    if (e < E) atomicAdd(&deg[dst[e]], ew[e]);
}

__global__ __launch_bounds__(256) void k_dinv(
    const float* __restrict__ deg, float* __restrict__ dinv, int n)
{
    int i = blockIdx.x * 256 + threadIdx.x;
    if (i < n) dinv[i] = rsqrtf(deg[i] + 1.0f);   // self-loop weight 1 => deg>0 always
}

// ---------------- build padded-ELL adjacency grouped by dst ------------------
__global__ __launch_bounds__(256) void k_fill(
    const int* __restrict__ src, const int* __restrict__ dst,
    const float* __restrict__ ew, const float* __restrict__ dinv,
    int* __restrict__ cnt, int* __restrict__ ell_src, float* __restrict__ ell_nrm,
    int E)
{
    int e = blockIdx.x * 256 + threadIdx.x;
    if (e >= E) return;
    int s = src[e], d = dst[e];
    int slot = atomicAdd(&cnt[d], 1);
    if (slot < MAXDEG) {
        ell_src[d * MAXDEG + slot] = s;
        ell_nrm[d * MAXDEG + slot] = dinv[s] * ew[e] * dinv[d];
    }
}

// ---------------- zero the pad slots up to the next multiple of 8 ------------
// Lets k_agg read 8 entries/iter: pad norms are 0.0 (contribute nothing),
// pad srcs are 0 (valid row). Deterministic.
__global__ __launch_bounds__(256) void k_pad(
    const int* __restrict__ cnt, int* __restrict__ ell_src,
    float* __restrict__ ell_nrm, int n)
{
    int idx = blockIdx.x * 256 + threadIdx.x;
    int i = idx >> 3, t = idx & 7;
    if (i >= n) return;
    int m  = min(cnt[i], MAXDEG);
    int m8 = min((m + 7) & ~7, MAXDEG);
    int slot = m + t;
    if (slot < m8) {
        ell_src[i * MAXDEG + slot] = 0;
        ell_nrm[i * MAXDEG + slot] = 0.f;
    }
}

// ---------------- C[n][128] = A[n][128] @ W[128][128] ------------------------
// Register-tiled: thread = 8 rows x 4 cols (32 acc). W f32 staged in LDS.
__global__ __launch_bounds__(256, 2) void k_gemm(
    const float* __restrict__ A, const float* __restrict__ W,
    float* __restrict__ C, int n)
{
    __shared__ float Ws[128 * 128];
    {
        const float4* __restrict__ Wv = (const float4*)W;
        float4* Sv = (float4*)Ws;
        #pragma unroll
        for (int i = 0; i < 16; ++i)
            Sv[threadIdx.x + i * 256] = Wv[threadIdx.x + i * 256];
    }
    __syncthreads();

    const int col0 = (threadIdx.x & 31) * 4;   // 32 threads cover 128 cols
    const int rg   = threadIdx.x >> 5;         // 0..7 row-groups of 8
    const int row0 = blockIdx.x * 64 + rg * 8;
    const int rowEnd = min(blockIdx.x * 64 + 64, n);

    const float* ap[8];
    #pragma unroll
    for (int r = 0; r < 8; ++r)
        ap[r] = A + (size_t)min(row0 + r, n - 1) * 128;

    float acc[8][4];
    #pragma unroll
    for (int r = 0; r < 8; ++r)
        #pragma unroll
        for (int c = 0; c < 4; ++c) acc[r][c] = 0.f;

    for (int k = 0; k < 128; k += 4) {
        float4 w0 = *(const float4*)&Ws[(k + 0) * 128 + col0];
        float4 w1 = *(const float4*)&Ws[(k + 1) * 128 + col0];
        float4 w2 = *(const float4*)&Ws[(k + 2) * 128 + col0];
        float4 w3 = *(const float4*)&Ws[(k + 3) * 128 + col0];
        #pragma unroll
        for (int r = 0; r < 8; ++r) {
            const float4 av = *(const float4*)&ap[r][k];
            acc[r][0] = fmaf(av.x, w0.x, acc[r][0]);
            acc[r][1] = fmaf(av.x, w0.y, acc[r][1]);
            acc[r][2] = fmaf(av.x, w0.z, acc[r][2]);
            acc[r][3] = fmaf(av.x, w0.w, acc[r][3]);
            acc[r][0] = fmaf(av.y, w1.x, acc[r][0]);
            acc[r][1] = fmaf(av.y, w1.y, acc[r][1]);
            acc[r][2] = fmaf(av.y, w1.z, acc[r][2]);
            acc[r][3] = fmaf(av.y, w1.w, acc[r][3]);
            acc[r][0] = fmaf(av.z, w2.x, acc[r][0]);
            acc[r][1] = fmaf(av.z, w2.y, acc[r][1]);
            acc[r][2] = fmaf(av.z, w2.z, acc[r][2]);
            acc[r][3] = fmaf(av.z, w2.w, acc[r][3]);
            acc[r][0] = fmaf(av.w, w3.x, acc[r][0]);
            acc[r][1] = fmaf(av.w, w3.y, acc[r][1]);
            acc[r][2] = fmaf(av.w, w3.z, acc[r][2]);
            acc[r][3] = fmaf(av.w, w3.w, acc[r][3]);
        }
    }

    #pragma unroll
    for (int r = 0; r < 8; ++r) {
        const int row = row0 + r;
        if (row < rowEnd) {
            float4 o; o.x = acc[r][0]; o.y = acc[r][1]; o.z = acc[r][2]; o.w = acc[r][3];
            *(float4*)&C[(size_t)row * 128 + col0] = o;
        }
    }
}

// ---------------- aggregation: out[i] = sum_e norm*h[src] + dinv[i]^2*h[i] + b
// one wave per dst node; 8 edges per iteration -> 8 independent 512B gathers
// in flight (memory-level parallelism). Pad slots have norm 0 (see k_pad).
template <bool RELU>
__global__ __launch_bounds__(256) void k_agg(
    const float* __restrict__ h, const int* __restrict__ ell_src,
    const float* __restrict__ ell_nrm, const int* __restrict__ cnt,
    const float* __restrict__ dinv, const float* __restrict__ bias,
    float* __restrict__ out, int n)
{
    const int lane = threadIdx.x & 63;
    const int wv   = threadIdx.x >> 6;
    const int i    = blockIdx.x * 4 + wv;
    if (i >= n) return;
    const int f = lane * 2;
    float ax = 0.f, ay = 0.f;
    const int m    = min(cnt[i], MAXDEG);
    const int m8   = min((m + 7) & ~7, MAXDEG);
    const int base = i * MAXDEG;
    for (int j = 0; j < m8; j += 8) {
        const int4   sa = *(const int4*)  &ell_src[base + j];
        const int4   sb = *(const int4*)  &ell_src[base + j + 4];
        const float4 wa = *(const float4*)&ell_nrm[base + j];
        const float4 wb = *(const float4*)&ell_nrm[base + j + 4];
        const float2 g0 = *(const float2*)&h[(size_t)sa.x * 128 + f];
        const float2 g1 = *(const float2*)&h[(size_t)sa.y * 128 + f];
        const float2 g2 = *(const float2*)&h[(size_t)sa.z * 128 + f];
        const float2 g3 = *(const float2*)&h[(size_t)sa.w * 128 + f];
        const float2 g4 = *(const float2*)&h[(size_t)sb.x * 128 + f];
        const float2 g5 = *(const float2*)&h[(size_t)sb.y * 128 + f];
        const float2 g6 = *(const float2*)&h[(size_t)sb.z * 128 + f];
        const float2 g7 = *(const float2*)&h[(size_t)sb.w * 128 + f];
        ax = fmaf(wa.x, g0.x, ax); ay = fmaf(wa.x, g0.y, ay);
        ax = fmaf(wa.y, g1.x, ax); ay = fmaf(wa.y, g1.y, ay);
        ax = fmaf(wa.z, g2.x, ax); ay = fmaf(wa.z, g2.y, ay);
        ax = fmaf(wa.w, g3.x, ax); ay = fmaf(wa.w, g3.y, ay);
        ax = fmaf(wb.x, g4.x, ax); ay = fmaf(wb.x, g4.y, ay);
        ax = fmaf(wb.y, g5.x, ax); ay = fmaf(wb.y, g5.y, ay);
        ax = fmaf(wb.z, g6.x, ax); ay = fmaf(wb.z, g6.y, ay);
        ax = fmaf(wb.w, g7.x, ax); ay = fmaf(wb.w, g7.y, ay);
    }
    const float di = dinv[i];
    const float wl = di * di;
    const float2 hs = *(const float2*)&h[(size_t)i * 128 + f];
    ax = fmaf(wl, hs.x, ax);
    ay = fmaf(wl, hs.y, ay);
    const float2 bb = *(const float2*)&bias[f];
    ax += bb.x; ay += bb.y;
    if (RELU) { ax = fmaxf(ax, 0.f); ay = fmaxf(ay, 0.f); }
    float2 o; o.x = ax; o.y = ay;
    *(float2*)&out[(size_t)i * 128 + f] = o;
}

// ---------------- mean pool per graph: 1024 threads = 16 waves --------------
__global__ __launch_bounds__(1024) void k_pool(
    const float* __restrict__ h, const int* __restrict__ batch,
    float* __restrict__ gout, int n)
{
    const int gi   = blockIdx.x;
    const int lane = threadIdx.x & 63;
    const int wv   = threadIdx.x >> 6;        // 0..15
    __shared__ int sse[2];
    __shared__ float red[16 * 128];
    if (threadIdx.x < 2) {
        const int target = gi + (int)threadIdx.x;
        int lo = 0, hi = n;
        while (lo < hi) { int m = (lo + hi) >> 1; if (batch[m] < target) lo = m + 1; else hi = m; }
        sse[threadIdx.x] = lo;
    }
    __syncthreads();
    const int ss = sse[0], se = sse[1];
    const int f = lane * 2;
    float ax = 0.f, ay = 0.f;
    for (int i = ss + wv; i < se; i += 16) {
        const float2 hv = *(const float2*)&h[(size_t)i * 128 + f];
        ax += hv.x; ay += hv.y;
    }
    red[wv * 128 + f]     = ax;
    red[wv * 128 + f + 1] = ay;
    __syncthreads();
    if (threadIdx.x < 128) {
        const int t = threadIdx.x;
        float acc = 0.f;
        #pragma unroll
        for (int j = 0; j < 16; ++j) acc += red[j * 128 + t];
        const float c = (float)(se - ss);
        gout[gi * 128 + t] = acc / fmaxf(c, 1.f);
    }
}

// ---------------- fused head: Linear->ReLU->LayerNorm->Linear ----------------
__global__ __launch_bounds__(128) void k_head(
    const float* __restrict__ g, const float* __restrict__ l1W,
    const float* __restrict__ l1b, const float* __restrict__ gamma,
    const float* __restrict__ beta, const float* __restrict__ l2W,
    const float* __restrict__ l2b, float* __restrict__ out)
{
    const int gi = blockIdx.x;
    const int t  = threadIdx.x;      // 128 threads
    __shared__ float gs[128], zs[128], red[128];
    gs[t] = g[gi * 128 + t];
    __syncthreads();
    float acc = l1b[t];
    for (int k = 0; k < 128; ++k) acc = fmaf(gs[k], l1W[k * 128 + t], acc);
    acc = fmaxf(acc, 0.f);
    red[t] = acc; __syncthreads();
    for (int off = 64; off > 0; off >>= 1) {
        if (t < off) red[t] += red[t + off];
        __syncthreads();
    }
    const float mu = red[0] * (1.f / 128.f);
    __syncthreads();
    const float d = acc - mu;
    red[t] = d * d; __syncthreads();
    for (int off = 64; off > 0; off >>= 1) {
        if (t < off) red[t] += red[t + off];
        __syncthreads();
    }
    const float var = red[0] * (1.f / 128.f);
    const float z = (acc - mu) * rsqrtf(var + 1e-5f) * gamma[t] + beta[t];
    zs[t] = z;
    __syncthreads();
    if (t < 16) {
        float o = l2b[t];
        for (int k = 0; k < 128; ++k) o = fmaf(zs[k], l2W[k * 16 + t], o);
        out[gi * 16 + t] = o;
    }
}

extern "C" void kernel_launch(void* const* d_in, const int* in_sizes, int n_in,
                              void* d_out, int out_size, void* d_ws, size_t ws_size,
                              hipStream_t stream)
{
    const float* x    = (const float*)d_in[0];
    const int*   ei   = (const int*)  d_in[1];
    const float* ew   = (const float*)d_in[2];
    const int*   bidx = (const int*)  d_in[3];
    const float* W1   = (const float*)d_in[4];
    const float* b1   = (const float*)d_in[5];
    const float* W2   = (const float*)d_in[6];
    const float* b2   = (const float*)d_in[7];
    const float* l1W  = (const float*)d_in[8];
    const float* l1b  = (const float*)d_in[9];
    const float* gam  = (const float*)d_in[10];
    const float* bet  = (const float*)d_in[11];
    const float* l2W  = (const float*)d_in[12];
    const float* l2b  = (const float*)d_in[13];
    float* out = (float*)d_out;

    const int E = in_sizes[2];              // edge_weight count
    const int n = in_sizes[3];              // batch_idx count = N nodes
    const int* e_src = ei;                  // edge_index[0]
    const int* e_dst = ei + E;              // edge_index[1]

    char* p = (char*)d_ws;
    auto alloc = [&](size_t bytes) { char* r = p; p += (bytes + 255) & ~(size_t)255; return r; };
    float* h_a   = (float*)alloc((size_t)n * 128 * 4);
    float* h_b   = (float*)alloc((size_t)n * 128 * 4);
    int*   ell_s = (int*)  alloc((size_t)n * MAXDEG * 4);
    float* ell_n = (float*)alloc((size_t)n * MAXDEG * 4);
    float* deg   = (float*)alloc((size_t)n * 4);
    float* dinv  = (float*)alloc((size_t)n * 4);
    int*   cnt   = (int*)  alloc((size_t)n * 4);
    float* gp    = (float*)alloc((size_t)128 * 128 * 4);

    hipMemsetAsync(deg, 0, (size_t)n * 4, stream);
    hipMemsetAsync(cnt, 0, (size_t)n * 4, stream);

    const int gE = (E + 255) / 256;
    const int gN = (n + 255) / 256;

    k_deg <<<gE, 256, 0, stream>>>(e_dst, ew, deg, E);
    k_dinv<<<gN, 256, 0, stream>>>(deg, dinv, n);
    k_fill<<<gE, 256, 0, stream>>>(e_src, e_dst, ew, dinv, cnt, ell_s, ell_n, E);
    k_pad <<<(n * 8 + 255) / 256, 256, 0, stream>>>(cnt, ell_s, ell_n, n);

    const int NB = (n + 63) / 64;           // one 64-row tile per block
    k_gemm<<<NB, 256, 0, stream>>>(x, W1, h_a, n);
    k_agg<true> <<<(n + 3) / 4, 256, 0, stream>>>(h_a, ell_s, ell_n, cnt, dinv, b1, h_b, n);
    k_gemm<<<NB, 256, 0, stream>>>(h_b, W2, h_a, n);
    k_agg<false><<<(n + 3) / 4, 256, 0, stream>>>(h_a, ell_s, ell_n, cnt, dinv, b2, h_b, n);

    k_pool<<<128, 1024, 0, stream>>>(h_b, bidx, gp, n);
    k_head<<<128, 128, 0, stream>>>(gp, l1W, l1b, gam, bet, l2W, l2b, out);
}

// Round 6
// 272.676 us; speedup vs baseline: 2.0788x; 1.0146x over previous
//
#include <hip/hip_runtime.h>

constexpr int MAXDEG = 64;

// ---------------- degree accumulation (dst side), 4 edges/thread -------------
__global__ __launch_bounds__(256) void k_deg(
    const int* __restrict__ dst, const float* __restrict__ ew,
    float* __restrict__ deg, int E)
{
    int e0 = (blockIdx.x * 256 + threadIdx.x) * 4;
    if (e0 + 3 < E) {
        const int4   d4 = *(const int4*)  &dst[e0];
        const float4 w4 = *(const float4*)&ew[e0];
        atomicAdd(&deg[d4.x], w4.x);
        atomicAdd(&deg[d4.y], w4.y);
        atomicAdd(&deg[d4.z], w4.z);
        atomicAdd(&deg[d4.w], w4.w);
    } else {
        for (int e = e0; e < E; ++e) atomicAdd(&deg[dst[e]], ew[e]);
    }
}

// ---------------- build padded-ELL (AoS {src, norm}) by dst, 4 edges/thread --
// norm computed on the fly from deg (self-loop +1 => deg+1 > 0 always).
__global__ __launch_bounds__(256) void k_fill(
    const int* __restrict__ src, const int* __restrict__ dst,
    const float* __restrict__ ew, const float* __restrict__ deg,
    int* __restrict__ cnt, uint2* __restrict__ ell, int E)
{
    int e0 = (blockIdx.x * 256 + threadIdx.x) * 4;
    if (e0 + 3 < E) {
        const int4   s4 = *(const int4*)  &src[e0];
        const int4   d4 = *(const int4*)  &dst[e0];
        const float4 w4 = *(const float4*)&ew[e0];
        int sl0 = atomicAdd(&cnt[d4.x], 1);
        int sl1 = atomicAdd(&cnt[d4.y], 1);
        int sl2 = atomicAdd(&cnt[d4.z], 1);
        int sl3 = atomicAdd(&cnt[d4.w], 1);
        float n0 = rsqrtf(deg[s4.x] + 1.f) * w4.x * rsqrtf(deg[d4.x] + 1.f);
        float n1 = rsqrtf(deg[s4.y] + 1.f) * w4.y * rsqrtf(deg[d4.y] + 1.f);
        float n2 = rsqrtf(deg[s4.z] + 1.f) * w4.z * rsqrtf(deg[d4.z] + 1.f);
        float n3 = rsqrtf(deg[s4.w] + 1.f) * w4.w * rsqrtf(deg[d4.w] + 1.f);
        if (sl0 < MAXDEG) ell[d4.x * MAXDEG + sl0] = make_uint2((unsigned)s4.x, __float_as_uint(n0));
        if (sl1 < MAXDEG) ell[d4.y * MAXDEG + sl1] = make_uint2((unsigned)s4.y, __float_as_uint(n1));
        if (sl2 < MAXDEG) ell[d4.z * MAXDEG + sl2] = make_uint2((unsigned)s4.z, __float_as_uint(n2));
        if (sl3 < MAXDEG) ell[d4.w * MAXDEG + sl3] = make_uint2((unsigned)s4.w, __float_as_uint(n3));
    } else {
        for (int e = e0; e < E; ++e) {
            int s = src[e], d = dst[e];
            int slot = atomicAdd(&cnt[d], 1);
            if (slot < MAXDEG) {
                float nm = rsqrtf(deg[s] + 1.f) * ew[e] * rsqrtf(deg[d] + 1.f);
                ell[d * MAXDEG + slot] = make_uint2((unsigned)s, __float_as_uint(nm));
            }
        }
    }
}

// ---------------- zero pad slots up to the next multiple of 8 ----------------
__global__ __launch_bounds__(256) void k_pad(
    const int* __restrict__ cnt, uint2* __restrict__ ell, int n)
{
    int idx = blockIdx.x * 256 + threadIdx.x;
    int i = idx >> 3, t = idx & 7;
    if (i >= n) return;
    int m  = min(cnt[i], MAXDEG);
    int m8 = min((m + 7) & ~7, MAXDEG);
    int slot = m + t;
    if (slot < m8) ell[i * MAXDEG + slot] = make_uint2(0u, 0u);  // norm 0 => no-op
}

// ---------------- C[n][128] = A[n][128] @ W[128][128] ------------------------
// Register-tiled: thread = 8 rows x 4 cols (32 acc). W f32 staged in LDS.
__global__ __launch_bounds__(256, 2) void k_gemm(
    const float* __restrict__ A, const float* __restrict__ W,
    float* __restrict__ C, int n)
{
    __shared__ float Ws[128 * 128];
    {
        const float4* __restrict__ Wv = (const float4*)W;
        float4* Sv = (float4*)Ws;
        #pragma unroll
        for (int i = 0; i < 16; ++i)
            Sv[threadIdx.x + i * 256] = Wv[threadIdx.x + i * 256];
    }
    __syncthreads();

    const int col0 = (threadIdx.x & 31) * 4;   // 32 threads cover 128 cols
    const int rg   = threadIdx.x >> 5;         // 0..7 row-groups of 8
    const int row0 = blockIdx.x * 64 + rg * 8;
    const int rowEnd = min(blockIdx.x * 64 + 64, n);

    const float* ap[8];
    #pragma unroll
    for (int r = 0; r < 8; ++r)
        ap[r] = A + (size_t)min(row0 + r, n - 1) * 128;

    float acc[8][4];
    #pragma unroll
    for (int r = 0; r < 8; ++r)
        #pragma unroll
        for (int c = 0; c < 4; ++c) acc[r][c] = 0.f;

    for (int k = 0; k < 128; k += 4) {
        float4 w0 = *(const float4*)&Ws[(k + 0) * 128 + col0];
        float4 w1 = *(const float4*)&Ws[(k + 1) * 128 + col0];
        float4 w2 = *(const float4*)&Ws[(k + 2) * 128 + col0];
        float4 w3 = *(const float4*)&Ws[(k + 3) * 128 + col0];
        #pragma unroll
        for (int r = 0; r < 8; ++r) {
            const float4 av = *(const float4*)&ap[r][k];
            acc[r][0] = fmaf(av.x, w0.x, acc[r][0]);
            acc[r][1] = fmaf(av.x, w0.y, acc[r][1]);
            acc[r][2] = fmaf(av.x, w0.z, acc[r][2]);
            acc[r][3] = fmaf(av.x, w0.w, acc[r][3]);
            acc[r][0] = fmaf(av.y, w1.x, acc[r][0]);
            acc[r][1] = fmaf(av.y, w1.y, acc[r][1]);
            acc[r][2] = fmaf(av.y, w1.z, acc[r][2]);
            acc[r][3] = fmaf(av.y, w1.w, acc[r][3]);
            acc[r][0] = fmaf(av.z, w2.x, acc[r][0]);
            acc[r][1] = fmaf(av.z, w2.y, acc[r][1]);
            acc[r][2] = fmaf(av.z, w2.z, acc[r][2]);
            acc[r][3] = fmaf(av.z, w2.w, acc[r][3]);
            acc[r][0] = fmaf(av.w, w3.x, acc[r][0]);
            acc[r][1] = fmaf(av.w, w3.y, acc[r][1]);
            acc[r][2] = fmaf(av.w, w3.z, acc[r][2]);
            acc[r][3] = fmaf(av.w, w3.w, acc[r][3]);
        }
    }

    #pragma unroll
    for (int r = 0; r < 8; ++r) {
        const int row = row0 + r;
        if (row < rowEnd) {
            float4 o; o.x = acc[r][0]; o.y = acc[r][1]; o.z = acc[r][2]; o.w = acc[r][3];
            *(float4*)&C[(size_t)row * 128 + col0] = o;
        }
    }
}

// ---------------- aggregation: out[i] = sum_e norm*h[src] + wl*h[i] + b ------
// one wave per dst node; 8 AoS edges/iter -> 8 independent 512B gathers.
template <bool RELU>
__global__ __launch_bounds__(256) void k_agg(
    const float* __restrict__ h, const uint2* __restrict__ ell,
    const int* __restrict__ cnt, const float* __restrict__ deg,
    const float* __restrict__ bias, float* __restrict__ out, int n)
{
    const int lane = threadIdx.x & 63;
    const int wv   = threadIdx.x >> 6;
    const int i    = blockIdx.x * 4 + wv;
    if (i >= n) return;
    const int f = lane * 2;
    float ax = 0.f, ay = 0.f;
    const int m    = min(cnt[i], MAXDEG);
    const int m8   = min((m + 7) & ~7, MAXDEG);
    const int base = i * MAXDEG;
    for (int j = 0; j < m8; j += 8) {
        const uint4 p0 = *(const uint4*)&ell[base + j];      // entries j, j+1
        const uint4 p1 = *(const uint4*)&ell[base + j + 2];
        const uint4 p2 = *(const uint4*)&ell[base + j + 4];
        const uint4 p3 = *(const uint4*)&ell[base + j + 6];
        const float2 g0 = *(const float2*)&h[(size_t)p0.x * 128 + f];
        const float2 g1 = *(const float2*)&h[(size_t)p0.z * 128 + f];
        const float2 g2 = *(const float2*)&h[(size_t)p1.x * 128 + f];
        const float2 g3 = *(const float2*)&h[(size_t)p1.z * 128 + f];
        const float2 g4 = *(const float2*)&h[(size_t)p2.x * 128 + f];
        const float2 g5 = *(const float2*)&h[(size_t)p2.z * 128 + f];
        const float2 g6 = *(const float2*)&h[(size_t)p3.x * 128 + f];
        const float2 g7 = *(const float2*)&h[(size_t)p3.z * 128 + f];
        const float w0 = __uint_as_float(p0.y), w1 = __uint_as_float(p0.w);
        const float w2 = __uint_as_float(p1.y), w3 = __uint_as_float(p1.w);
        const float w4 = __uint_as_float(p2.y), w5 = __uint_as_float(p2.w);
        const float w6 = __uint_as_float(p3.y), w7 = __uint_as_float(p3.w);
        ax = fmaf(w0, g0.x, ax); ay = fmaf(w0, g0.y, ay);
        ax = fmaf(w1, g1.x, ax); ay = fmaf(w1, g1.y, ay);
        ax = fmaf(w2, g2.x, ax); ay = fmaf(w2, g2.y, ay);
        ax = fmaf(w3, g3.x, ax); ay = fmaf(w3, g3.y, ay);
        ax = fmaf(w4, g4.x, ax); ay = fmaf(w4, g4.y, ay);
        ax = fmaf(w5, g5.x, ax); ay = fmaf(w5, g5.y, ay);
        ax = fmaf(w6, g6.x, ax); ay = fmaf(w6, g6.y, ay);
        ax = fmaf(w7, g7.x, ax); ay = fmaf(w7, g7.y, ay);
    }
    const float di = rsqrtf(deg[i] + 1.f);
    const float wl = di * di;
    const float2 hs = *(const float2*)&h[(size_t)i * 128 + f];
    ax = fmaf(wl, hs.x, ax);
    ay = fmaf(wl, hs.y, ay);
    const float2 bb = *(const float2*)&bias[f];
    ax += bb.x; ay += bb.y;
    if (RELU) { ax = fmaxf(ax, 0.f); ay = fmaxf(ay, 0.f); }
    float2 o; o.x = ax; o.y = ay;
    *(float2*)&out[(size_t)i * 128 + f] = o;
}

// ---------------- mean pool per graph: 1024 threads = 16 waves --------------
__global__ __launch_bounds__(1024) void k_pool(
    const float* __restrict__ h, const int* __restrict__ batch,
    float* __restrict__ gout, int n)
{
    const int gi   = blockIdx.x;
    const int lane = threadIdx.x & 63;
    const int wv   = threadIdx.x >> 6;        // 0..15
    __shared__ int sse[2];
    __shared__ float red[16 * 128];
    if (threadIdx.x < 2) {
        const int target = gi + (int)threadIdx.x;
        int lo = 0, hi = n;
        while (lo < hi) { int m = (lo + hi) >> 1; if (batch[m] < target) lo = m + 1; else hi = m; }
        sse[threadIdx.x] = lo;
    }
    __syncthreads();
    const int ss = sse[0], se = sse[1];
    const int f = lane * 2;
    float ax = 0.f, ay = 0.f;
    for (int i = ss + wv; i < se; i += 16) {
        const float2 hv = *(const float2*)&h[(size_t)i * 128 + f];
        ax += hv.x; ay += hv.y;
    }
    red[wv * 128 + f]     = ax;
    red[wv * 128 + f + 1] = ay;
    __syncthreads();
    if (threadIdx.x < 128) {
        const int t = threadIdx.x;
        float acc = 0.f;
        #pragma unroll
        for (int j = 0; j < 16; ++j) acc += red[j * 128 + t];
        const float c = (float)(se - ss);
        gout[gi * 128 + t] = acc / fmaxf(c, 1.f);
    }
}

// ---------------- fused head: Linear->ReLU->LayerNorm->Linear ----------------
__global__ __launch_bounds__(128) void k_head(
    const float* __restrict__ g, const float* __restrict__ l1W,
    const float* __restrict__ l1b, const float* __restrict__ gamma,
    const float* __restrict__ beta, const float* __restrict__ l2W,
    const float* __restrict__ l2b, float* __restrict__ out)
{
    const int gi = blockIdx.x;
    const int t  = threadIdx.x;      // 128 threads
    __shared__ float gs[128], zs[128], red[128];
    gs[t] = g[gi * 128 + t];
    __syncthreads();
    float acc = l1b[t];
    for (int k = 0; k < 128; ++k) acc = fmaf(gs[k], l1W[k * 128 + t], acc);
    acc = fmaxf(acc, 0.f);
    red[t] = acc; __syncthreads();
    for (int off = 64; off > 0; off >>= 1) {
        if (t < off) red[t] += red[t + off];
        __syncthreads();
    }
    const float mu = red[0] * (1.f / 128.f);
    __syncthreads();
    const float d = acc - mu;
    red[t] = d * d; __syncthreads();
    for (int off = 64; off > 0; off >>= 1) {
        if (t < off) red[t] += red[t + off];
        __syncthreads();
    }
    const float var = red[0] * (1.f / 128.f);
    const float z = (acc - mu) * rsqrtf(var + 1e-5f) * gamma[t] + beta[t];
    zs[t] = z;
    __syncthreads();
    if (t < 16) {
        float o = l2b[t];
        for (int k = 0; k < 128; ++k) o = fmaf(zs[k], l2W[k * 16 + t], o);
        out[gi * 16 + t] = o;
    }
}

extern "C" void kernel_launch(void* const* d_in, const int* in_sizes, int n_in,
                              void* d_out, int out_size, void* d_ws, size_t ws_size,
                              hipStream_t stream)
{
    const float* x    = (const float*)d_in[0];
    const int*   ei   = (const int*)  d_in[1];
    const float* ew   = (const float*)d_in[2];
    const int*   bidx = (const int*)  d_in[3];
    const float* W1   = (const float*)d_in[4];
    const float* b1   = (const float*)d_in[5];
    const float* W2   = (const float*)d_in[6];
    const float* b2   = (const float*)d_in[7];
    const float* l1W  = (const float*)d_in[8];
    const float* l1b  = (const float*)d_in[9];
    const float* gam  = (const float*)d_in[10];
    const float* bet  = (const float*)d_in[11];
    const float* l2W  = (const float*)d_in[12];
    const float* l2b  = (const float*)d_in[13];
    float* out = (float*)d_out;

    const int E = in_sizes[2];              // edge_weight count
    const int n = in_sizes[3];              // batch_idx count = N nodes
    const int* e_src = ei;                  // edge_index[0]
    const int* e_dst = ei + E;              // edge_index[1]

    char* p = (char*)d_ws;
    auto alloc = [&](size_t bytes) { char* r = p; p += (bytes + 255) & ~(size_t)255; return r; };
    float* h_a  = (float*)alloc((size_t)n * 128 * 4);
    float* h_b  = (float*)alloc((size_t)n * 128 * 4);
    uint2* ell  = (uint2*)alloc((size_t)n * MAXDEG * 8);
    float* deg  = (float*)alloc((size_t)n * 4);
    int*   cnt  = (int*)  alloc((size_t)n * 4);
    float* gp   = (float*)alloc((size_t)128 * 128 * 4);

    hipMemsetAsync(deg, 0, (size_t)n * 4, stream);
    hipMemsetAsync(cnt, 0, (size_t)n * 4, stream);

    const int gE4 = (E / 4 + 255) / 256 + 1;

    k_deg <<<gE4, 256, 0, stream>>>(e_dst, ew, deg, E);
    k_fill<<<gE4, 256, 0, stream>>>(e_src, e_dst, ew, deg, cnt, ell, E);
    k_pad <<<(n * 8 + 255) / 256, 256, 0, stream>>>(cnt, ell, n);

    const int NB = (n + 63) / 64;           // one 64-row tile per block
    k_gemm<<<NB, 256, 0, stream>>>(x, W1, h_a, n);
    k_agg<true> <<<(n + 3) / 4, 256, 0, stream>>>(h_a, ell, cnt, deg, b1, h_b, n);
    k_gemm<<<NB, 256, 0, stream>>>(h_b, W2, h_a, n);
    k_agg<false><<<(n + 3) / 4, 256, 0, stream>>>(h_a, ell, cnt, deg, b2, h_b, n);

    k_pool<<<128, 1024, 0, stream>>>(h_b, bidx, gp, n);
    k_head<<<128, 128, 0, stream>>>(gp, l1W, l1b, gam, bet, l2W, l2b, out);
}

// Round 7
// 240.736 us; speedup vs baseline: 2.3547x; 1.1327x over previous
//
#include <hip/hip_runtime.h>
#include <hip/hip_bf16.h>

constexpr int MAXDEG = 64;

__device__ inline float bf_lo(unsigned u) { return __uint_as_float(u << 16); }
__device__ inline float bf_hi(unsigned u) { return __uint_as_float(u & 0xffff0000u); }
__device__ inline unsigned bf_pack(float a, float b) {
    __hip_bfloat162 t = __float22bfloat162_rn(make_float2(a, b));
    return *reinterpret_cast<unsigned*>(&t);
}

// ---------------- degree accumulation (dst side), 4 edges/thread -------------
__global__ __launch_bounds__(256) void k_deg(
    const int* __restrict__ dst, const float* __restrict__ ew,
    float* __restrict__ deg, int E)
{
    int e0 = (blockIdx.x * 256 + threadIdx.x) * 4;
    if (e0 + 3 < E) {
        const int4   d4 = *(const int4*)  &dst[e0];
        const float4 w4 = *(const float4*)&ew[e0];
        atomicAdd(&deg[d4.x], w4.x);
        atomicAdd(&deg[d4.y], w4.y);
        atomicAdd(&deg[d4.z], w4.z);
        atomicAdd(&deg[d4.w], w4.w);
    } else {
        for (int e = e0; e < E; ++e) atomicAdd(&deg[dst[e]], ew[e]);
    }
}

// ---------------- build padded-ELL (AoS {src, norm}) by dst, 4 edges/thread --
__global__ __launch_bounds__(256) void k_fill(
    const int* __restrict__ src, const int* __restrict__ dst,
    const float* __restrict__ ew, const float* __restrict__ deg,
    int* __restrict__ cnt, uint2* __restrict__ ell, int E)
{
    int e0 = (blockIdx.x * 256 + threadIdx.x) * 4;
    if (e0 + 3 < E) {
        const int4   s4 = *(const int4*)  &src[e0];
        const int4   d4 = *(const int4*)  &dst[e0];
        const float4 w4 = *(const float4*)&ew[e0];
        int sl0 = atomicAdd(&cnt[d4.x], 1);
        int sl1 = atomicAdd(&cnt[d4.y], 1);
        int sl2 = atomicAdd(&cnt[d4.z], 1);
        int sl3 = atomicAdd(&cnt[d4.w], 1);
        float n0 = rsqrtf(deg[s4.x] + 1.f) * w4.x * rsqrtf(deg[d4.x] + 1.f);
        float n1 = rsqrtf(deg[s4.y] + 1.f) * w4.y * rsqrtf(deg[d4.y] + 1.f);
        float n2 = rsqrtf(deg[s4.z] + 1.f) * w4.z * rsqrtf(deg[d4.z] + 1.f);
        float n3 = rsqrtf(deg[s4.w] + 1.f) * w4.w * rsqrtf(deg[d4.w] + 1.f);
        if (sl0 < MAXDEG) ell[d4.x * MAXDEG + sl0] = make_uint2((unsigned)s4.x, __float_as_uint(n0));
        if (sl1 < MAXDEG) ell[d4.y * MAXDEG + sl1] = make_uint2((unsigned)s4.y, __float_as_uint(n1));
        if (sl2 < MAXDEG) ell[d4.z * MAXDEG + sl2] = make_uint2((unsigned)s4.z, __float_as_uint(n2));
        if (sl3 < MAXDEG) ell[d4.w * MAXDEG + sl3] = make_uint2((unsigned)s4.w, __float_as_uint(n3));
    } else {
        for (int e = e0; e < E; ++e) {
            int s = src[e], d = dst[e];
            int slot = atomicAdd(&cnt[d], 1);
            if (slot < MAXDEG) {
                float nm = rsqrtf(deg[s] + 1.f) * ew[e] * rsqrtf(deg[d] + 1.f);
                ell[d * MAXDEG + slot] = make_uint2((unsigned)s, __float_as_uint(nm));
            }
        }
    }
}

// ---------------- zero pad slots up to the next multiple of 8 ----------------
__global__ __launch_bounds__(256) void k_pad(
    const int* __restrict__ cnt, uint2* __restrict__ ell, int n)
{
    int idx = blockIdx.x * 256 + threadIdx.x;
    int i = idx >> 3, t = idx & 7;
    if (i >= n) return;
    int m  = min(cnt[i], MAXDEG);
    int m8 = min((m + 7) & ~7, MAXDEG);
    int slot = m + t;
    if (slot < m8) ell[i * MAXDEG + slot] = make_uint2(0u, 0u);  // norm 0 => no-op
}

// ---------------- C[n][128] = A[n][128] @ W[128][128], C in bf16 -------------
// k-split LDS staging (32 KB) -> 4 blocks/CU = 16 waves/CU (was 2 blk / 8 wv).
// Thread = 8 rows x 4 cols (32 f32 acc). A is f32 (gemm1) or bf16 (gemm2).
template <bool IN_BF16>
__global__ __launch_bounds__(256, 4) void k_gemm(
    const void* __restrict__ Ain, const float* __restrict__ W,
    unsigned short* __restrict__ C, int n)
{
    __shared__ float Ws[64 * 128];                 // 32 KB: half of W (64 k-rows)
    const float*          Af = (const float*)Ain;
    const unsigned short* Ab = (const unsigned short*)Ain;

    const int col0 = (threadIdx.x & 31) * 4;       // 32 threads cover 128 cols
    const int rg   = threadIdx.x >> 5;             // 0..7 row-groups of 8
    const int row0 = blockIdx.x * 64 + rg * 8;
    const int rowEnd = min(blockIdx.x * 64 + 64, n);

    size_t arow[8];
    #pragma unroll
    for (int r = 0; r < 8; ++r)
        arow[r] = (size_t)min(row0 + r, n - 1) * 128;

    float acc[8][4];
    #pragma unroll
    for (int r = 0; r < 8; ++r)
        #pragma unroll
        for (int c = 0; c < 4; ++c) acc[r][c] = 0.f;

    #pragma unroll
    for (int kb = 0; kb < 2; ++kb) {
        __syncthreads();                           // prev compute done (no-op on kb=0)
        {   // stage W[kb*64 .. kb*64+64) : 2048 float4, 8 per thread
            const float4* Wv = (const float4*)(W + kb * 64 * 128);
            float4* Sv = (float4*)Ws;
            #pragma unroll
            for (int i = 0; i < 8; ++i)
                Sv[threadIdx.x + i * 256] = Wv[threadIdx.x + i * 256];
        }
        __syncthreads();

        for (int k = 0; k < 64; k += 4) {
            const int kk = kb * 64 + k;
            float4 w0 = *(const float4*)&Ws[(k + 0) * 128 + col0];
            float4 w1 = *(const float4*)&Ws[(k + 1) * 128 + col0];
            float4 w2 = *(const float4*)&Ws[(k + 2) * 128 + col0];
            float4 w3 = *(const float4*)&Ws[(k + 3) * 128 + col0];
            #pragma unroll
            for (int r = 0; r < 8; ++r) {
                float4 av;
                if constexpr (!IN_BF16) {
                    av = *(const float4*)(Af + arow[r] + kk);
                } else {
                    const uint2 u = *(const uint2*)(Ab + arow[r] + kk);
                    av.x = bf_lo(u.x); av.y = bf_hi(u.x);
                    av.z = bf_lo(u.y); av.w = bf_hi(u.y);
                }
                acc[r][0] = fmaf(av.x, w0.x, acc[r][0]);
                acc[r][1] = fmaf(av.x, w0.y, acc[r][1]);
                acc[r][2] = fmaf(av.x, w0.z, acc[r][2]);
                acc[r][3] = fmaf(av.x, w0.w, acc[r][3]);
                acc[r][0] = fmaf(av.y, w1.x, acc[r][0]);
                acc[r][1] = fmaf(av.y, w1.y, acc[r][1]);
                acc[r][2] = fmaf(av.y, w1.z, acc[r][2]);
                acc[r][3] = fmaf(av.y, w1.w, acc[r][3]);
                acc[r][0] = fmaf(av.z, w2.x, acc[r][0]);
                acc[r][1] = fmaf(av.z, w2.y, acc[r][1]);
                acc[r][2] = fmaf(av.z, w2.z, acc[r][2]);
                acc[r][3] = fmaf(av.z, w2.w, acc[r][3]);
                acc[r][0] = fmaf(av.w, w3.x, acc[r][0]);
                acc[r][1] = fmaf(av.w, w3.y, acc[r][1]);
                acc[r][2] = fmaf(av.w, w3.z, acc[r][2]);
                acc[r][3] = fmaf(av.w, w3.w, acc[r][3]);
            }
        }
    }

    #pragma unroll
    for (int r = 0; r < 8; ++r) {
        const int row = row0 + r;
        if (row < rowEnd) {
            uint2 o;
            o.x = bf_pack(acc[r][0], acc[r][1]);
            o.y = bf_pack(acc[r][2], acc[r][3]);
            *(uint2*)&C[(size_t)row * 128 + col0] = o;
        }
    }
}

// ---------------- aggregation over bf16 h, f32 accumulate --------------------
// one wave per dst node; 8 AoS edges/iter -> 8 independent 256B gathers.
template <bool RELU, bool OUT_BF16>
__global__ __launch_bounds__(256) void k_agg(
    const unsigned short* __restrict__ h, const uint2* __restrict__ ell,
    const int* __restrict__ cnt, const float* __restrict__ deg,
    const float* __restrict__ bias, void* __restrict__ outv, int n)
{
    const int lane = threadIdx.x & 63;
    const int wv   = threadIdx.x >> 6;
    const int i    = blockIdx.x * 4 + wv;
    if (i >= n) return;
    const int f = lane * 2;
    float ax = 0.f, ay = 0.f;
    const int m    = min(cnt[i], MAXDEG);
    const int m8   = min((m + 7) & ~7, MAXDEG);
    const int base = i * MAXDEG;
    for (int j = 0; j < m8; j += 8) {
        const uint4 p0 = *(const uint4*)&ell[base + j];      // entries j, j+1
        const uint4 p1 = *(const uint4*)&ell[base + j + 2];
        const uint4 p2 = *(const uint4*)&ell[base + j + 4];
        const uint4 p3 = *(const uint4*)&ell[base + j + 6];
        const unsigned g0 = *(const unsigned*)&h[(size_t)p0.x * 128 + f];
        const unsigned g1 = *(const unsigned*)&h[(size_t)p0.z * 128 + f];
        const unsigned g2 = *(const unsigned*)&h[(size_t)p1.x * 128 + f];
        const unsigned g3 = *(const unsigned*)&h[(size_t)p1.z * 128 + f];
        const unsigned g4 = *(const unsigned*)&h[(size_t)p2.x * 128 + f];
        const unsigned g5 = *(const unsigned*)&h[(size_t)p2.z * 128 + f];
        const unsigned g6 = *(const unsigned*)&h[(size_t)p3.x * 128 + f];
        const unsigned g7 = *(const unsigned*)&h[(size_t)p3.z * 128 + f];
        const float w0 = __uint_as_float(p0.y), w1 = __uint_as_float(p0.w);
        const float w2 = __uint_as_float(p1.y), w3 = __uint_as_float(p1.w);
        const float w4 = __uint_as_float(p2.y), w5 = __uint_as_float(p2.w);
        const float w6 = __uint_as_float(p3.y), w7 = __uint_as_float(p3.w);
        ax = fmaf(w0, bf_lo(g0), ax); ay = fmaf(w0, bf_hi(g0), ay);
        ax = fmaf(w1, bf_lo(g1), ax); ay = fmaf(w1, bf_hi(g1), ay);
        ax = fmaf(w2, bf_lo(g2), ax); ay = fmaf(w2, bf_hi(g2), ay);
        ax = fmaf(w3, bf_lo(g3), ax); ay = fmaf(w3, bf_hi(g3), ay);
        ax = fmaf(w4, bf_lo(g4), ax); ay = fmaf(w4, bf_hi(g4), ay);
        ax = fmaf(w5, bf_lo(g5), ax); ay = fmaf(w5, bf_hi(g5), ay);
        ax = fmaf(w6, bf_lo(g6), ax); ay = fmaf(w6, bf_hi(g6), ay);
        ax = fmaf(w7, bf_lo(g7), ax); ay = fmaf(w7, bf_hi(g7), ay);
    }
    const float di = rsqrtf(deg[i] + 1.f);
    const float wl = di * di;
    const unsigned hs = *(const unsigned*)&h[(size_t)i * 128 + f];
    ax = fmaf(wl, bf_lo(hs), ax);
    ay = fmaf(wl, bf_hi(hs), ay);
    const float2 bb = *(const float2*)&bias[f];
    ax += bb.x; ay += bb.y;
    if (RELU) { ax = fmaxf(ax, 0.f); ay = fmaxf(ay, 0.f); }
    if constexpr (OUT_BF16) {
        ((unsigned*)outv)[((size_t)i * 128 + f) >> 1] = bf_pack(ax, ay);
    } else {
        float2 o; o.x = ax; o.y = ay;
        *(float2*)&((float*)outv)[(size_t)i * 128 + f] = o;
    }
}

// ---------------- mean pool per graph: 1024 threads = 16 waves --------------
__global__ __launch_bounds__(1024) void k_pool(
    const float* __restrict__ h, const int* __restrict__ batch,
    float* __restrict__ gout, int n)
{
    const int gi   = blockIdx.x;
    const int lane = threadIdx.x & 63;
    const int wv   = threadIdx.x >> 6;        // 0..15
    __shared__ int sse[2];
    __shared__ float red[16 * 128];
    if (threadIdx.x < 2) {
        const int target = gi + (int)threadIdx.x;
        int lo = 0, hi = n;
        while (lo < hi) { int m = (lo + hi) >> 1; if (batch[m] < target) lo = m + 1; else hi = m; }
        sse[threadIdx.x] = lo;
    }
    __syncthreads();
    const int ss = sse[0], se = sse[1];
    const int f = lane * 2;
    float ax = 0.f, ay = 0.f;
    for (int i = ss + wv; i < se; i += 16) {
        const float2 hv = *(const float2*)&h[(size_t)i * 128 + f];
        ax += hv.x; ay += hv.y;
    }
    red[wv * 128 + f]     = ax;
    red[wv * 128 + f + 1] = ay;
    __syncthreads();
    if (threadIdx.x < 128) {
        const int t = threadIdx.x;
        float acc = 0.f;
        #pragma unroll
        for (int j = 0; j < 16; ++j) acc += red[j * 128 + t];
        const float c = (float)(se - ss);
        gout[gi * 128 + t] = acc / fmaxf(c, 1.f);
    }
}

// ---------------- fused head: Linear->ReLU->LayerNorm->Linear ----------------
__global__ __launch_bounds__(128) void k_head(
    const float* __restrict__ g, const float* __restrict__ l1W,
    const float* __restrict__ l1b, const float* __restrict__ gamma,
    const float* __restrict__ beta, const float* __restrict__ l2W,
    const float* __restrict__ l2b, float* __restrict__ out)
{
    const int gi = blockIdx.x;
    const int t  = threadIdx.x;      // 128 threads
    __shared__ float gs[128], zs[128], red[128];
    gs[t] = g[gi * 128 + t];
    __syncthreads();
    float acc = l1b[t];
    for (int k = 0; k < 128; ++k) acc = fmaf(gs[k], l1W[k * 128 + t], acc);
    acc = fmaxf(acc, 0.f);
    red[t] = acc; __syncthreads();
    for (int off = 64; off > 0; off >>= 1) {
        if (t < off) red[t] += red[t + off];
        __syncthreads();
    }
    const float mu = red[0] * (1.f / 128.f);
    __syncthreads();
    const float d = acc - mu;
    red[t] = d * d; __syncthreads();
    for (int off = 64; off > 0; off >>= 1) {
        if (t < off) red[t] += red[t + off];
        __syncthreads();
    }
    const float var = red[0] * (1.f / 128.f);
    const float z = (acc - mu) * rsqrtf(var + 1e-5f) * gamma[t] + beta[t];
    zs[t] = z;
    __syncthreads();
    if (t < 16) {
        float o = l2b[t];
        for (int k = 0; k < 128; ++k) o = fmaf(zs[k], l2W[k * 16 + t], o);
        out[gi * 16 + t] = o;
    }
}

extern "C" void kernel_launch(void* const* d_in, const int* in_sizes, int n_in,
                              void* d_out, int out_size, void* d_ws, size_t ws_size,
                              hipStream_t stream)
{
    const float* x    = (const float*)d_in[0];
    const int*   ei   = (const int*)  d_in[1];
    const float* ew   = (const float*)d_in[2];
    const int*   bidx = (const int*)  d_in[3];
    const float* W1   = (const float*)d_in[4];
    const float* b1   = (const float*)d_in[5];
    const float* W2   = (const float*)d_in[6];
    const float* b2   = (const float*)d_in[7];
    const float* l1W  = (const float*)d_in[8];
    const float* l1b  = (const float*)d_in[9];
    const float* gam  = (const float*)d_in[10];
    const float* bet  = (const float*)d_in[11];
    const float* l2W  = (const float*)d_in[12];
    const float* l2b  = (const float*)d_in[13];
    float* out = (float*)d_out;

    const int E = in_sizes[2];              // edge_weight count
    const int n = in_sizes[3];              // batch_idx count = N nodes
    const int* e_src = ei;                  // edge_index[0]
    const int* e_dst = ei + E;              // edge_index[1]

    char* p = (char*)d_ws;
    auto alloc = [&](size_t bytes) { char* r = p; p += (bytes + 255) & ~(size_t)255; return r; };
    unsigned short* h16_a = (unsigned short*)alloc((size_t)n * 128 * 2);  // gemm1 out / gemm2 out
    unsigned short* h16_b = (unsigned short*)alloc((size_t)n * 128 * 2);  // agg1 out (relu'd)
    float* hf    = (float*)alloc((size_t)n * 128 * 4);                    // agg2 out (f32)
    uint2* ell   = (uint2*)alloc((size_t)n * MAXDEG * 8);
    float* deg   = (float*)alloc((size_t)n * 4);
    int*   cnt   = (int*)  alloc((size_t)n * 4);
    float* gp    = (float*)alloc((size_t)128 * 128 * 4);

    hipMemsetAsync(deg, 0, (size_t)n * 4, stream);
    hipMemsetAsync(cnt, 0, (size_t)n * 4, stream);

    const int gE4 = (E / 4 + 255) / 256 + 1;

    k_deg <<<gE4, 256, 0, stream>>>(e_dst, ew, deg, E);
    k_fill<<<gE4, 256, 0, stream>>>(e_src, e_dst, ew, deg, cnt, ell, E);
    k_pad <<<(n * 8 + 255) / 256, 256, 0, stream>>>(cnt, ell, n);

    const int NB = (n + 63) / 64;           // one 64-row tile per block
    k_gemm<false><<<NB, 256, 0, stream>>>(x,     W1, h16_a, n);
    k_agg<true, true> <<<(n + 3) / 4, 256, 0, stream>>>(h16_a, ell, cnt, deg, b1, h16_b, n);
    k_gemm<true> <<<NB, 256, 0, stream>>>(h16_b, W2, h16_a, n);
    k_agg<false, false><<<(n + 3) / 4, 256, 0, stream>>>(h16_a, ell, cnt, deg, b2, hf, n);

    k_pool<<<128, 1024, 0, stream>>>(hf, bidx, gp, n);
    k_head<<<128, 128, 0, stream>>>(gp, l1W, l1b, gam, bet, l2W, l2b, out);
}

// Round 8
// 184.276 us; speedup vs baseline: 3.0761x; 1.3064x over previous
//
#include <hip/hip_runtime.h>
#include <hip/hip_bf16.h>

constexpr int MAXDEG = 64;

typedef __attribute__((ext_vector_type(8))) short short8;
typedef __attribute__((ext_vector_type(4))) float f32x4;

__device__ inline float bf_lo(unsigned u) { return __uint_as_float(u << 16); }
__device__ inline float bf_hi(unsigned u) { return __uint_as_float(u & 0xffff0000u); }
__device__ inline unsigned bf_pack(float a, float b) {
    __hip_bfloat162 t = __float22bfloat162_rn(make_float2(a, b));
    return *reinterpret_cast<unsigned*>(&t);
}
__device__ inline unsigned short bf1(float a) {
    __hip_bfloat16 t = __float2bfloat16(a);
    return *reinterpret_cast<unsigned short*>(&t);
}

// ---------------- degree accumulation (dst side), 4 edges/thread -------------
__global__ __launch_bounds__(256) void k_deg(
    const int* __restrict__ dst, const float* __restrict__ ew,
    float* __restrict__ deg, int E)
{
    int e0 = (blockIdx.x * 256 + threadIdx.x) * 4;
    if (e0 + 3 < E) {
        const int4   d4 = *(const int4*)  &dst[e0];
        const float4 w4 = *(const float4*)&ew[e0];
        atomicAdd(&deg[d4.x], w4.x);
        atomicAdd(&deg[d4.y], w4.y);
        atomicAdd(&deg[d4.z], w4.z);
        atomicAdd(&deg[d4.w], w4.w);
    } else {
        for (int e = e0; e < E; ++e) atomicAdd(&deg[dst[e]], ew[e]);
    }
}

// ---------------- build padded-ELL (AoS {src, norm}) by dst, 4 edges/thread --
__global__ __launch_bounds__(256) void k_fill(
    const int* __restrict__ src, const int* __restrict__ dst,
    const float* __restrict__ ew, const float* __restrict__ deg,
    int* __restrict__ cnt, uint2* __restrict__ ell, int E)
{
    int e0 = (blockIdx.x * 256 + threadIdx.x) * 4;
    if (e0 + 3 < E) {
        const int4   s4 = *(const int4*)  &src[e0];
        const int4   d4 = *(const int4*)  &dst[e0];
        const float4 w4 = *(const float4*)&ew[e0];
        int sl0 = atomicAdd(&cnt[d4.x], 1);
        int sl1 = atomicAdd(&cnt[d4.y], 1);
        int sl2 = atomicAdd(&cnt[d4.z], 1);
        int sl3 = atomicAdd(&cnt[d4.w], 1);
        float n0 = rsqrtf(deg[s4.x] + 1.f) * w4.x * rsqrtf(deg[d4.x] + 1.f);
        float n1 = rsqrtf(deg[s4.y] + 1.f) * w4.y * rsqrtf(deg[d4.y] + 1.f);
        float n2 = rsqrtf(deg[s4.z] + 1.f) * w4.z * rsqrtf(deg[d4.z] + 1.f);
        float n3 = rsqrtf(deg[s4.w] + 1.f) * w4.w * rsqrtf(deg[d4.w] + 1.f);
        if (sl0 < MAXDEG) ell[d4.x * MAXDEG + sl0] = make_uint2((unsigned)s4.x, __float_as_uint(n0));
        if (sl1 < MAXDEG) ell[d4.y * MAXDEG + sl1] = make_uint2((unsigned)s4.y, __float_as_uint(n1));
        if (sl2 < MAXDEG) ell[d4.z * MAXDEG + sl2] = make_uint2((unsigned)s4.z, __float_as_uint(n2));
        if (sl3 < MAXDEG) ell[d4.w * MAXDEG + sl3] = make_uint2((unsigned)s4.w, __float_as_uint(n3));
    } else {
        for (int e = e0; e < E; ++e) {
            int s = src[e], d = dst[e];
            int slot = atomicAdd(&cnt[d], 1);
            if (slot < MAXDEG) {
                float nm = rsqrtf(deg[s] + 1.f) * ew[e] * rsqrtf(deg[d] + 1.f);
                ell[d * MAXDEG + slot] = make_uint2((unsigned)s, __float_as_uint(nm));
            }
        }
    }
}

// ---------------- zero pad slots up to the next multiple of 8 ----------------
__global__ __launch_bounds__(256) void k_pad(
    const int* __restrict__ cnt, uint2* __restrict__ ell, int n)
{
    int idx = blockIdx.x * 256 + threadIdx.x;
    int i = idx >> 3, t = idx & 7;
    if (i >= n) return;
    int m  = min(cnt[i], MAXDEG);
    int m8 = min((m + 7) & ~7, MAXDEG);
    int slot = m + t;
    if (slot < m8) ell[i * MAXDEG + slot] = make_uint2(0u, 0u);  // norm 0 => no-op
}

// ---------------- W[128k][128n] f32 -> Wt[128n][128k] bf16 -------------------
__global__ __launch_bounds__(256) void k_wcast(
    const float* __restrict__ W, unsigned short* __restrict__ Wt)
{
    int idx = blockIdx.x * 256 + threadIdx.x;   // 16384 elems
    int k = idx >> 7, nn = idx & 127;
    Wt[nn * 128 + k] = bf1(W[k * 128 + nn]);
}

// ---------------- MFMA GEMM: C[n][128](bf16) = A[n][128] @ W ----------------
// Wt = W^T bf16 staged in LDS with XOR seg-swizzle (bank-conflict-free frags).
// 4 waves x 16 rows = 64 rows/block. Per wave: 8 col-tiles x 4 k-slices = 32
// mfma_f32_16x16x32_bf16. A-frag: lane(r,kg) reads A[m0+r][ks*32+kg*8..+7].
// C/D layout (m89): col=lane&15, row=(lane>>4)*4+reg.
template <bool IN_BF16>
__global__ __launch_bounds__(256, 4) void k_gemm(
    const void* __restrict__ Ain, const unsigned short* __restrict__ Wt,
    unsigned short* __restrict__ C, int n)
{
    __shared__ unsigned short Ws[128 * 128];    // 32 KB
    {   // stage Wt: 2048 uint4; swizzle seg^(row&7) in 16B units
        const uint4* Wv = (const uint4*)Wt;
        uint4* Sv = (uint4*)Ws;
        #pragma unroll
        for (int i = threadIdx.x; i < 2048; i += 256) {
            int row = i >> 4, seg = i & 15;
            Sv[row * 16 + (seg ^ (row & 7))] = Wv[i];
        }
    }
    __syncthreads();

    const float*          Af = (const float*)Ain;
    const unsigned short* Ab = (const unsigned short*)Ain;

    const int wid  = threadIdx.x >> 6;          // 0..3
    const int lane = threadIdx.x & 63;
    const int r    = lane & 15;
    const int kg   = lane >> 4;                 // 0..3
    const int m0   = blockIdx.x * 64 + wid * 16;
    const size_t arow = (size_t)min(m0 + r, n - 1) * 128;

    f32x4 acc[8];
    #pragma unroll
    for (int ct = 0; ct < 8; ++ct) acc[ct] = (f32x4){0.f, 0.f, 0.f, 0.f};

    const short8* Ws8 = (const short8*)Ws;

    #pragma unroll
    for (int ks = 0; ks < 4; ++ks) {
        const int k0 = ks * 32 + kg * 8;
        short8 afrag;
        if constexpr (IN_BF16) {
            afrag = *(const short8*)(Ab + arow + k0);
        } else {
            const float4 lo = *(const float4*)(Af + arow + k0);
            const float4 hi = *(const float4*)(Af + arow + k0 + 4);
            union { short8 s; uint4 u; } cvt;
            cvt.u = make_uint4(bf_pack(lo.x, lo.y), bf_pack(lo.z, lo.w),
                               bf_pack(hi.x, hi.y), bf_pack(hi.z, hi.w));
            afrag = cvt.s;
        }
        const int segi = ks * 4 + kg;
        #pragma unroll
        for (int ct = 0; ct < 8; ++ct) {
            const int ncol = ct * 16 + r;
            const short8 bfrag = Ws8[ncol * 16 + (segi ^ (ncol & 7))];
            acc[ct] = __builtin_amdgcn_mfma_f32_16x16x32_bf16(afrag, bfrag, acc[ct], 0, 0, 0);
        }
    }

    #pragma unroll
    for (int ct = 0; ct < 8; ++ct) {
        #pragma unroll
        for (int reg = 0; reg < 4; ++reg) {
            const int row = m0 + kg * 4 + reg;
            if (row < n) C[(size_t)row * 128 + ct * 16 + r] = bf1(acc[ct][reg]);
        }
    }
}

// ---------------- aggregation over bf16 h, f32 accumulate --------------------
template <bool RELU, bool OUT_BF16>
__global__ __launch_bounds__(256) void k_agg(
    const unsigned short* __restrict__ h, const uint2* __restrict__ ell,
    const int* __restrict__ cnt, const float* __restrict__ deg,
    const float* __restrict__ bias, void* __restrict__ outv, int n)
{
    const int lane = threadIdx.x & 63;
    const int wv   = threadIdx.x >> 6;
    const int i    = blockIdx.x * 4 + wv;
    if (i >= n) return;
    const int f = lane * 2;
    float ax = 0.f, ay = 0.f;
    const int m    = min(cnt[i], MAXDEG);
    const int m8   = min((m + 7) & ~7, MAXDEG);
    const int base = i * MAXDEG;
    for (int j = 0; j < m8; j += 8) {
        const uint4 p0 = *(const uint4*)&ell[base + j];      // entries j, j+1
        const uint4 p1 = *(const uint4*)&ell[base + j + 2];
        const uint4 p2 = *(const uint4*)&ell[base + j + 4];
        const uint4 p3 = *(const uint4*)&ell[base + j + 6];
        const unsigned g0 = *(const unsigned*)&h[(size_t)p0.x * 128 + f];
        const unsigned g1 = *(const unsigned*)&h[(size_t)p0.z * 128 + f];
        const unsigned g2 = *(const unsigned*)&h[(size_t)p1.x * 128 + f];
        const unsigned g3 = *(const unsigned*)&h[(size_t)p1.z * 128 + f];
        const unsigned g4 = *(const unsigned*)&h[(size_t)p2.x * 128 + f];
        const unsigned g5 = *(const unsigned*)&h[(size_t)p2.z * 128 + f];
        const unsigned g6 = *(const unsigned*)&h[(size_t)p3.x * 128 + f];
        const unsigned g7 = *(const unsigned*)&h[(size_t)p3.z * 128 + f];
        const float w0 = __uint_as_float(p0.y), w1 = __uint_as_float(p0.w);
        const float w2 = __uint_as_float(p1.y), w3 = __uint_as_float(p1.w);
        const float w4 = __uint_as_float(p2.y), w5 = __uint_as_float(p2.w);
        const float w6 = __uint_as_float(p3.y), w7 = __uint_as_float(p3.w);
        ax = fmaf(w0, bf_lo(g0), ax); ay = fmaf(w0, bf_hi(g0), ay);
        ax = fmaf(w1, bf_lo(g1), ax); ay = fmaf(w1, bf_hi(g1), ay);
        ax = fmaf(w2, bf_lo(g2), ax); ay = fmaf(w2, bf_hi(g2), ay);
        ax = fmaf(w3, bf_lo(g3), ax); ay = fmaf(w3, bf_hi(g3), ay);
        ax = fmaf(w4, bf_lo(g4), ax); ay = fmaf(w4, bf_hi(g4), ay);
        ax = fmaf(w5, bf_lo(g5), ax); ay = fmaf(w5, bf_hi(g5), ay);
        ax = fmaf(w6, bf_lo(g6), ax); ay = fmaf(w6, bf_hi(g6), ay);
        ax = fmaf(w7, bf_lo(g7), ax); ay = fmaf(w7, bf_hi(g7), ay);
    }
    const float di = rsqrtf(deg[i] + 1.f);
    const float wl = di * di;
    const unsigned hs = *(const unsigned*)&h[(size_t)i * 128 + f];
    ax = fmaf(wl, bf_lo(hs), ax);
    ay = fmaf(wl, bf_hi(hs), ay);
    const float2 bb = *(const float2*)&bias[f];
    ax += bb.x; ay += bb.y;
    if (RELU) { ax = fmaxf(ax, 0.f); ay = fmaxf(ay, 0.f); }
    if constexpr (OUT_BF16) {
        ((unsigned*)outv)[((size_t)i * 128 + f) >> 1] = bf_pack(ax, ay);
    } else {
        float2 o; o.x = ax; o.y = ay;
        *(float2*)&((float*)outv)[(size_t)i * 128 + f] = o;
    }
}

// ---------------- mean pool per graph: 1024 threads = 16 waves --------------
__global__ __launch_bounds__(1024) void k_pool(
    const float* __restrict__ h, const int* __restrict__ batch,
    float* __restrict__ gout, int n)
{
    const int gi   = blockIdx.x;
    const int lane = threadIdx.x & 63;
    const int wv   = threadIdx.x >> 6;        // 0..15
    __shared__ int sse[2];
    __shared__ float red[16 * 128];
    if (threadIdx.x < 2) {
        const int target = gi + (int)threadIdx.x;
        int lo = 0, hi = n;
        while (lo < hi) { int m = (lo + hi) >> 1; if (batch[m] < target) lo = m + 1; else hi = m; }
        sse[threadIdx.x] = lo;
    }
    __syncthreads();
    const int ss = sse[0], se = sse[1];
    const int f = lane * 2;
    float ax = 0.f, ay = 0.f;
    for (int i = ss + wv; i < se; i += 16) {
        const float2 hv = *(const float2*)&h[(size_t)i * 128 + f];
        ax += hv.x; ay += hv.y;
    }
    red[wv * 128 + f]     = ax;
    red[wv * 128 + f + 1] = ay;
    __syncthreads();
    if (threadIdx.x < 128) {
        const int t = threadIdx.x;
        float acc = 0.f;
        #pragma unroll
        for (int j = 0; j < 16; ++j) acc += red[j * 128 + t];
        const float c = (float)(se - ss);
        gout[gi * 128 + t] = acc / fmaxf(c, 1.f);
    }
}

// ---------------- fused head: Linear->ReLU->LayerNorm->Linear ----------------
__global__ __launch_bounds__(128) void k_head(
    const float* __restrict__ g, const float* __restrict__ l1W,
    const float* __restrict__ l1b, const float* __restrict__ gamma,
    const float* __restrict__ beta, const float* __restrict__ l2W,
    const float* __restrict__ l2b, float* __restrict__ out)
{
    const int gi = blockIdx.x;
    const int t  = threadIdx.x;      // 128 threads
    __shared__ float gs[128], zs[128], red[128];
    gs[t] = g[gi * 128 + t];
    __syncthreads();
    float acc = l1b[t];
    for (int k = 0; k < 128; ++k) acc = fmaf(gs[k], l1W[k * 128 + t], acc);
    acc = fmaxf(acc, 0.f);
    red[t] = acc; __syncthreads();
    for (int off = 64; off > 0; off >>= 1) {
        if (t < off) red[t] += red[t + off];
        __syncthreads();
    }
    const float mu = red[0] * (1.f / 128.f);
    __syncthreads();
    const float d = acc - mu;
    red[t] = d * d; __syncthreads();
    for (int off = 64; off > 0; off >>= 1) {
        if (t < off) red[t] += red[t + off];
        __syncthreads();
    }
    const float var = red[0] * (1.f / 128.f);
    const float z = (acc - mu) * rsqrtf(var + 1e-5f) * gamma[t] + beta[t];
    zs[t] = z;
    __syncthreads();
    if (t < 16) {
        float o = l2b[t];
        for (int k = 0; k < 128; ++k) o = fmaf(zs[k], l2W[k * 16 + t], o);
        out[gi * 16 + t] = o;
    }
}

extern "C" void kernel_launch(void* const* d_in, const int* in_sizes, int n_in,
                              void* d_out, int out_size, void* d_ws, size_t ws_size,
                              hipStream_t stream)
{
    const float* x    = (const float*)d_in[0];
    const int*   ei   = (const int*)  d_in[1];
    const float* ew   = (const float*)d_in[2];
    const int*   bidx = (const int*)  d_in[3];
    const float* W1   = (const float*)d_in[4];
    const float* b1   = (const float*)d_in[5];
    const float* W2   = (const float*)d_in[6];
    const float* b2   = (const float*)d_in[7];
    const float* l1W  = (const float*)d_in[8];
    const float* l1b  = (const float*)d_in[9];
    const float* gam  = (const float*)d_in[10];
    const float* bet  = (const float*)d_in[11];
    const float* l2W  = (const float*)d_in[12];
    const float* l2b  = (const float*)d_in[13];
    float* out = (float*)d_out;

    const int E = in_sizes[2];              // edge_weight count
    const int n = in_sizes[3];              // batch_idx count = N nodes
    const int* e_src = ei;                  // edge_index[0]
    const int* e_dst = ei + E;              // edge_index[1]

    char* p = (char*)d_ws;
    auto alloc = [&](size_t bytes) { char* r = p; p += (bytes + 255) & ~(size_t)255; return r; };
    unsigned short* h16_a = (unsigned short*)alloc((size_t)n * 128 * 2);  // gemm1 out / gemm2 out
    unsigned short* h16_b = (unsigned short*)alloc((size_t)n * 128 * 2);  // agg1 out (relu'd)
    float* hf    = (float*)alloc((size_t)n * 128 * 4);                    // agg2 out (f32)
    uint2* ell   = (uint2*)alloc((size_t)n * MAXDEG * 8);
    float* deg   = (float*)alloc((size_t)n * 4);
    int*   cnt   = (int*)  alloc((size_t)n * 4);
    float* gp    = (float*)alloc((size_t)128 * 128 * 4);
    unsigned short* W1t = (unsigned short*)alloc((size_t)128 * 128 * 2);
    unsigned short* W2t = (unsigned short*)alloc((size_t)128 * 128 * 2);

    hipMemsetAsync(deg, 0, (size_t)n * 4, stream);
    hipMemsetAsync(cnt, 0, (size_t)n * 4, stream);

    const int gE4 = (E / 4 + 255) / 256 + 1;

    k_wcast<<<64, 256, 0, stream>>>(W1, W1t);
    k_wcast<<<64, 256, 0, stream>>>(W2, W2t);
    k_deg <<<gE4, 256, 0, stream>>>(e_dst, ew, deg, E);
    k_fill<<<gE4, 256, 0, stream>>>(e_src, e_dst, ew, deg, cnt, ell, E);
    k_pad <<<(n * 8 + 255) / 256, 256, 0, stream>>>(cnt, ell, n);

    const int NB = (n + 63) / 64;           // one 64-row tile per block
    k_gemm<false><<<NB, 256, 0, stream>>>(x,     W1t, h16_a, n);
    k_agg<true, true> <<<(n + 3) / 4, 256, 0, stream>>>(h16_a, ell, cnt, deg, b1, h16_b, n);
    k_gemm<true> <<<NB, 256, 0, stream>>>(h16_b, W2t, h16_a, n);
    k_agg<false, false><<<(n + 3) / 4, 256, 0, stream>>>(h16_a, ell, cnt, deg, b2, hf, n);

    k_pool<<<128, 1024, 0, stream>>>(hf, bidx, gp, n);
    k_head<<<128, 128, 0, stream>>>(gp, l1W, l1b, gam, bet, l2W, l2b, out);
}

// Round 9
// 183.592 us; speedup vs baseline: 3.0876x; 1.0037x over previous
//
#include <hip/hip_runtime.h>
#include <hip/hip_bf16.h>

constexpr int MAXDEG = 64;

typedef __attribute__((ext_vector_type(8))) short short8;
typedef __attribute__((ext_vector_type(4))) float f32x4;

__device__ inline float bf_lo(unsigned u) { return __uint_as_float(u << 16); }
__device__ inline float bf_hi(unsigned u) { return __uint_as_float(u & 0xffff0000u); }
__device__ inline unsigned bf_pack(float a, float b) {
    __hip_bfloat162 t = __float22bfloat162_rn(make_float2(a, b));
    return *reinterpret_cast<unsigned*>(&t);
}
__device__ inline unsigned short bf1(float a) {
    __hip_bfloat16 t = __float2bfloat16(a);
    return *reinterpret_cast<unsigned short*>(&t);
}

// ---------------- init: W1t/W2t transpose-cast + zero deg/cnt (one dispatch) -
__global__ __launch_bounds__(256) void k_init(
    const float* __restrict__ W1, const float* __restrict__ W2,
    unsigned short* __restrict__ W1t, unsigned short* __restrict__ W2t,
    float* __restrict__ deg, int* __restrict__ cnt, int n)
{
    int idx = blockIdx.x * 256 + threadIdx.x;
    if (idx < 16384) {
        int k = idx >> 7, nn = idx & 127;
        W1t[nn * 128 + k] = bf1(W1[k * 128 + nn]);
        W2t[nn * 128 + k] = bf1(W2[k * 128 + nn]);
    }
    if (idx < n) { deg[idx] = 0.f; cnt[idx] = 0; }
}

// ---------------- degree accumulation (dst side), 8 edges/thread -------------
__global__ __launch_bounds__(256) void k_deg(
    const int* __restrict__ dst, const float* __restrict__ ew,
    float* __restrict__ deg, int E)
{
    int e0 = (blockIdx.x * 256 + threadIdx.x) * 8;
    if (e0 + 7 < E) {
        const int4   da = *(const int4*)  &dst[e0];
        const int4   db = *(const int4*)  &dst[e0 + 4];
        const float4 wa = *(const float4*)&ew[e0];
        const float4 wb = *(const float4*)&ew[e0 + 4];
        atomicAdd(&deg[da.x], wa.x);
        atomicAdd(&deg[da.y], wa.y);
        atomicAdd(&deg[da.z], wa.z);
        atomicAdd(&deg[da.w], wa.w);
        atomicAdd(&deg[db.x], wb.x);
        atomicAdd(&deg[db.y], wb.y);
        atomicAdd(&deg[db.z], wb.z);
        atomicAdd(&deg[db.w], wb.w);
    } else {
        for (int e = e0; e < E; ++e) atomicAdd(&deg[dst[e]], ew[e]);
    }
}

// ---------------- build padded-ELL (AoS {src, norm}) by dst, 8 edges/thread --
__global__ __launch_bounds__(256) void k_fill(
    const int* __restrict__ src, const int* __restrict__ dst,
    const float* __restrict__ ew, const float* __restrict__ deg,
    int* __restrict__ cnt, uint2* __restrict__ ell, int E)
{
    int e0 = (blockIdx.x * 256 + threadIdx.x) * 8;
    if (e0 + 7 < E) {
        const int4   sa = *(const int4*)  &src[e0];
        const int4   sb = *(const int4*)  &src[e0 + 4];
        const int4   da = *(const int4*)  &dst[e0];
        const int4   db = *(const int4*)  &dst[e0 + 4];
        const float4 wa = *(const float4*)&ew[e0];
        const float4 wb = *(const float4*)&ew[e0 + 4];
        int sl0 = atomicAdd(&cnt[da.x], 1);
        int sl1 = atomicAdd(&cnt[da.y], 1);
        int sl2 = atomicAdd(&cnt[da.z], 1);
        int sl3 = atomicAdd(&cnt[da.w], 1);
        int sl4 = atomicAdd(&cnt[db.x], 1);
        int sl5 = atomicAdd(&cnt[db.y], 1);
        int sl6 = atomicAdd(&cnt[db.z], 1);
        int sl7 = atomicAdd(&cnt[db.w], 1);
        float n0 = rsqrtf(deg[sa.x] + 1.f) * wa.x * rsqrtf(deg[da.x] + 1.f);
        float n1 = rsqrtf(deg[sa.y] + 1.f) * wa.y * rsqrtf(deg[da.y] + 1.f);
        float n2 = rsqrtf(deg[sa.z] + 1.f) * wa.z * rsqrtf(deg[da.z] + 1.f);
        float n3 = rsqrtf(deg[sa.w] + 1.f) * wa.w * rsqrtf(deg[da.w] + 1.f);
        float n4 = rsqrtf(deg[sb.x] + 1.f) * wb.x * rsqrtf(deg[db.x] + 1.f);
        float n5 = rsqrtf(deg[sb.y] + 1.f) * wb.y * rsqrtf(deg[db.y] + 1.f);
        float n6 = rsqrtf(deg[sb.z] + 1.f) * wb.z * rsqrtf(deg[db.z] + 1.f);
        float n7 = rsqrtf(deg[sb.w] + 1.f) * wb.w * rsqrtf(deg[db.w] + 1.f);
        if (sl0 < MAXDEG) ell[da.x * MAXDEG + sl0] = make_uint2((unsigned)sa.x, __float_as_uint(n0));
        if (sl1 < MAXDEG) ell[da.y * MAXDEG + sl1] = make_uint2((unsigned)sa.y, __float_as_uint(n1));
        if (sl2 < MAXDEG) ell[da.z * MAXDEG + sl2] = make_uint2((unsigned)sa.z, __float_as_uint(n2));
        if (sl3 < MAXDEG) ell[da.w * MAXDEG + sl3] = make_uint2((unsigned)sa.w, __float_as_uint(n3));
        if (sl4 < MAXDEG) ell[db.x * MAXDEG + sl4] = make_uint2((unsigned)sb.x, __float_as_uint(n4));
        if (sl5 < MAXDEG) ell[db.y * MAXDEG + sl5] = make_uint2((unsigned)sb.y, __float_as_uint(n5));
        if (sl6 < MAXDEG) ell[db.z * MAXDEG + sl6] = make_uint2((unsigned)sb.z, __float_as_uint(n6));
        if (sl7 < MAXDEG) ell[db.w * MAXDEG + sl7] = make_uint2((unsigned)sb.w, __float_as_uint(n7));
    } else {
        for (int e = e0; e < E; ++e) {
            int s = src[e], d = dst[e];
            int slot = atomicAdd(&cnt[d], 1);
            if (slot < MAXDEG) {
                float nm = rsqrtf(deg[s] + 1.f) * ew[e] * rsqrtf(deg[d] + 1.f);
                ell[d * MAXDEG + slot] = make_uint2((unsigned)s, __float_as_uint(nm));
            }
        }
    }
}

// ---------------- zero pad slots up to the next multiple of 8 ----------------
__global__ __launch_bounds__(256) void k_pad(
    const int* __restrict__ cnt, uint2* __restrict__ ell, int n)
{
    int idx = blockIdx.x * 256 + threadIdx.x;
    int i = idx >> 3, t = idx & 7;
    if (i >= n) return;
    int m  = min(cnt[i], MAXDEG);
    int m8 = min((m + 7) & ~7, MAXDEG);
    int slot = m + t;
    if (slot < m8) ell[i * MAXDEG + slot] = make_uint2(0u, 0u);  // norm 0 => no-op
}

// ---------------- MFMA GEMM: C[n][128](bf16) = A[n][128] @ W ----------------
// Wt = W^T bf16 staged in LDS with XOR seg-swizzle (bank-conflict-free frags).
// 4 waves x 16 rows = 64 rows/block. Per wave: 8 col-tiles x 4 k-slices = 32
// mfma_f32_16x16x32_bf16. C/D layout (m89): col=lane&15, row=(lane>>4)*4+reg.
template <bool IN_BF16>
__global__ __launch_bounds__(256, 4) void k_gemm(
    const void* __restrict__ Ain, const unsigned short* __restrict__ Wt,
    unsigned short* __restrict__ C, int n)
{
    __shared__ unsigned short Ws[128 * 128];    // 32 KB
    {   // stage Wt: 2048 uint4; swizzle seg^(row&7) in 16B units
        const uint4* Wv = (const uint4*)Wt;
        uint4* Sv = (uint4*)Ws;
        #pragma unroll
        for (int i = threadIdx.x; i < 2048; i += 256) {
            int row = i >> 4, seg = i & 15;
            Sv[row * 16 + (seg ^ (row & 7))] = Wv[i];
        }
    }
    __syncthreads();

    const float*          Af = (const float*)Ain;
    const unsigned short* Ab = (const unsigned short*)Ain;

    const int wid  = threadIdx.x >> 6;          // 0..3
    const int lane = threadIdx.x & 63;
    const int r    = lane & 15;
    const int kg   = lane >> 4;                 // 0..3
    const int m0   = blockIdx.x * 64 + wid * 16;
    const size_t arow = (size_t)min(m0 + r, n - 1) * 128;

    f32x4 acc[8];
    #pragma unroll
    for (int ct = 0; ct < 8; ++ct) acc[ct] = (f32x4){0.f, 0.f, 0.f, 0.f};

    const short8* Ws8 = (const short8*)Ws;

    #pragma unroll
    for (int ks = 0; ks < 4; ++ks) {
        const int k0 = ks * 32 + kg * 8;
        short8 afrag;
        if constexpr (IN_BF16) {
            afrag = *(const short8*)(Ab + arow + k0);
        } else {
            const float4 lo = *(const float4*)(Af + arow + k0);
            const float4 hi = *(const float4*)(Af + arow + k0 + 4);
            union { short8 s; uint4 u; } cvt;
            cvt.u = make_uint4(bf_pack(lo.x, lo.y), bf_pack(lo.z, lo.w),
                               bf_pack(hi.x, hi.y), bf_pack(hi.z, hi.w));
            afrag = cvt.s;
        }
        const int segi = ks * 4 + kg;
        #pragma unroll
        for (int ct = 0; ct < 8; ++ct) {
            const int ncol = ct * 16 + r;
            const short8 bfrag = Ws8[ncol * 16 + (segi ^ (ncol & 7))];
            acc[ct] = __builtin_amdgcn_mfma_f32_16x16x32_bf16(afrag, bfrag, acc[ct], 0, 0, 0);
        }
    }

    #pragma unroll
    for (int ct = 0; ct < 8; ++ct) {
        #pragma unroll
        for (int reg = 0; reg < 4; ++reg) {
            const int row = m0 + kg * 4 + reg;
            if (row < n) C[(size_t)row * 128 + ct * 16 + r] = bf1(acc[ct][reg]);
        }
    }
}

// ---------------- aggregation over bf16 h, f32 accumulate --------------------
template <bool RELU, bool OUT_BF16>
__global__ __launch_bounds__(256) void k_agg(
    const unsigned short* __restrict__ h, const uint2* __restrict__ ell,
    const int* __restrict__ cnt, const float* __restrict__ deg,
    const float* __restrict__ bias, void* __restrict__ outv, int n)
{
    const int lane = threadIdx.x & 63;
    const int wv   = threadIdx.x >> 6;
    const int i    = blockIdx.x * 4 + wv;
    if (i >= n) return;
    const int f = lane * 2;
    float ax = 0.f, ay = 0.f;
    const int m    = min(cnt[i], MAXDEG);
    const int m8   = min((m + 7) & ~7, MAXDEG);
    const int base = i * MAXDEG;
    for (int j = 0; j < m8; j += 8) {
        const uint4 p0 = *(const uint4*)&ell[base + j];      // entries j, j+1
        const uint4 p1 = *(const uint4*)&ell[base + j + 2];
        const uint4 p2 = *(const uint4*)&ell[base + j + 4];
        const uint4 p3 = *(const uint4*)&ell[base + j + 6];
        const unsigned g0 = *(const unsigned*)&h[(size_t)p0.x * 128 + f];
        const unsigned g1 = *(const unsigned*)&h[(size_t)p0.z * 128 + f];
        const unsigned g2 = *(const unsigned*)&h[(size_t)p1.x * 128 + f];
        const unsigned g3 = *(const unsigned*)&h[(size_t)p1.z * 128 + f];
        const unsigned g4 = *(const unsigned*)&h[(size_t)p2.x * 128 + f];
        const unsigned g5 = *(const unsigned*)&h[(size_t)p2.z * 128 + f];
        const unsigned g6 = *(const unsigned*)&h[(size_t)p3.x * 128 + f];
        const unsigned g7 = *(const unsigned*)&h[(size_t)p3.z * 128 + f];
        const float w0 = __uint_as_float(p0.y), w1 = __uint_as_float(p0.w);
        const float w2 = __uint_as_float(p1.y), w3 = __uint_as_float(p1.w);
        const float w4 = __uint_as_float(p2.y), w5 = __uint_as_float(p2.w);
        const float w6 = __uint_as_float(p3.y), w7 = __uint_as_float(p3.w);
        ax = fmaf(w0, bf_lo(g0), ax); ay = fmaf(w0, bf_hi(g0), ay);
        ax = fmaf(w1, bf_lo(g1), ax); ay = fmaf(w1, bf_hi(g1), ay);
        ax = fmaf(w2, bf_lo(g2), ax); ay = fmaf(w2, bf_hi(g2), ay);
        ax = fmaf(w3, bf_lo(g3), ax); ay = fmaf(w3, bf_hi(g3), ay);
        ax = fmaf(w4, bf_lo(g4), ax); ay = fmaf(w4, bf_hi(g4), ay);
        ax = fmaf(w5, bf_lo(g5), ax); ay = fmaf(w5, bf_hi(g5), ay);
        ax = fmaf(w6, bf_lo(g6), ax); ay = fmaf(w6, bf_hi(g6), ay);
        ax = fmaf(w7, bf_lo(g7), ax); ay = fmaf(w7, bf_hi(g7), ay);
    }
    const float di = rsqrtf(deg[i] + 1.f);
    const float wl = di * di;
    const unsigned hs = *(const unsigned*)&h[(size_t)i * 128 + f];
    ax = fmaf(wl, bf_lo(hs), ax);
    ay = fmaf(wl, bf_hi(hs), ay);
    const float2 bb = *(const float2*)&bias[f];
    ax += bb.x; ay += bb.y;
    if (RELU) { ax = fmaxf(ax, 0.f); ay = fmaxf(ay, 0.f); }
    if constexpr (OUT_BF16) {
        ((unsigned*)outv)[((size_t)i * 128 + f) >> 1] = bf_pack(ax, ay);
    } else {
        float2 o; o.x = ax; o.y = ay;
        *(float2*)&((float*)outv)[(size_t)i * 128 + f] = o;
    }
}

// ---------------- mean pool per graph: 1024 threads = 16 waves --------------
__global__ __launch_bounds__(1024) void k_pool(
    const float* __restrict__ h, const int* __restrict__ batch,
    float* __restrict__ gout, int n)
{
    const int gi   = blockIdx.x;
    const int lane = threadIdx.x & 63;
    const int wv   = threadIdx.x >> 6;        // 0..15
    __shared__ int sse[2];
    __shared__ float red[16 * 128];
    if (threadIdx.x < 2) {
        const int target = gi + (int)threadIdx.x;
        int lo = 0, hi = n;
        while (lo < hi) { int m = (lo + hi) >> 1; if (batch[m] < target) lo = m + 1; else hi = m; }
        sse[threadIdx.x] = lo;
    }
    __syncthreads();
    const int ss = sse[0], se = sse[1];
    const int f = lane * 2;
    float ax = 0.f, ay = 0.f;
    for (int i = ss + wv; i < se; i += 16) {
        const float2 hv = *(const float2*)&h[(size_t)i * 128 + f];
        ax += hv.x; ay += hv.y;
    }
    red[wv * 128 + f]     = ax;
    red[wv * 128 + f + 1] = ay;
    __syncthreads();
    if (threadIdx.x < 128) {
        const int t = threadIdx.x;
        float acc = 0.f;
        #pragma unroll
        for (int j = 0; j < 16; ++j) acc += red[j * 128 + t];
        const float c = (float)(se - ss);
        gout[gi * 128 + t] = acc / fmaxf(c, 1.f);
    }
}

// ---------------- fused head: Linear->ReLU->LayerNorm->Linear ----------------
__global__ __launch_bounds__(128) void k_head(
    const float* __restrict__ g, const float* __restrict__ l1W,
    const float* __restrict__ l1b, const float* __restrict__ gamma,
    const float* __restrict__ beta, const float* __restrict__ l2W,
    const float* __restrict__ l2b, float* __restrict__ out)
{
    const int gi = blockIdx.x;
    const int t  = threadIdx.x;      // 128 threads
    __shared__ float gs[128], zs[128], red[128];
    gs[t] = g[gi * 128 + t];
    __syncthreads();
    float acc = l1b[t];
    for (int k = 0; k < 128; ++k) acc = fmaf(gs[k], l1W[k * 128 + t], acc);
    acc = fmaxf(acc, 0.f);
    red[t] = acc; __syncthreads();
    for (int off = 64; off > 0; off >>= 1) {
        if (t < off) red[t] += red[t + off];
        __syncthreads();
    }
    const float mu = red[0] * (1.f / 128.f);
    __syncthreads();
    const float d = acc - mu;
    red[t] = d * d; __syncthreads();
    for (int off = 64; off > 0; off >>= 1) {
        if (t < off) red[t] += red[t + off];
        __syncthreads();
    }
    const float var = red[0] * (1.f / 128.f);
    const float z = (acc - mu) * rsqrtf(var + 1e-5f) * gamma[t] + beta[t];
    zs[t] = z;
    __syncthreads();
    if (t < 16) {
        float o = l2b[t];
        for (int k = 0; k < 128; ++k) o = fmaf(zs[k], l2W[k * 16 + t], o);
        out[gi * 16 + t] = o;
    }
}

extern "C" void kernel_launch(void* const* d_in, const int* in_sizes, int n_in,
                              void* d_out, int out_size, void* d_ws, size_t ws_size,
                              hipStream_t stream)
{
    const float* x    = (const float*)d_in[0];
    const int*   ei   = (const int*)  d_in[1];
    const float* ew   = (const float*)d_in[2];
    const int*   bidx = (const int*)  d_in[3];
    const float* W1   = (const float*)d_in[4];
    const float* b1   = (const float*)d_in[5];
    const float* W2   = (const float*)d_in[6];
    const float* b2   = (const float*)d_in[7];
    const float* l1W  = (const float*)d_in[8];
    const float* l1b  = (const float*)d_in[9];
    const float* gam  = (const float*)d_in[10];
    const float* bet  = (const float*)d_in[11];
    const float* l2W  = (const float*)d_in[12];
    const float* l2b  = (const float*)d_in[13];
    float* out = (float*)d_out;

    const int E = in_sizes[2];              // edge_weight count
    const int n = in_sizes[3];              // batch_idx count = N nodes
    const int* e_src = ei;                  // edge_index[0]
    const int* e_dst = ei + E;              // edge_index[1]

    char* p = (char*)d_ws;
    auto alloc = [&](size_t bytes) { char* r = p; p += (bytes + 255) & ~(size_t)255; return r; };
    unsigned short* h16_a = (unsigned short*)alloc((size_t)n * 128 * 2);  // gemm1 out / gemm2 out
    unsigned short* h16_b = (unsigned short*)alloc((size_t)n * 128 * 2);  // agg1 out (relu'd)
    float* hf    = (float*)alloc((size_t)n * 128 * 4);                    // agg2 out (f32)
    uint2* ell   = (uint2*)alloc((size_t)n * MAXDEG * 8);
    float* deg   = (float*)alloc((size_t)n * 4);
    int*   cnt   = (int*)  alloc((size_t)n * 4);
    float* gp    = (float*)alloc((size_t)128 * 128 * 4);
    unsigned short* W1t = (unsigned short*)alloc((size_t)128 * 128 * 2);
    unsigned short* W2t = (unsigned short*)alloc((size_t)128 * 128 * 2);

    const int initWork = (n > 16384 ? n : 16384);
    k_init<<<(initWork + 255) / 256, 256, 0, stream>>>(W1, W2, W1t, W2t, deg, cnt, n);

    const int gE8 = (E / 8 + 255) / 256 + 1;
    k_deg <<<gE8, 256, 0, stream>>>(e_dst, ew, deg, E);
    k_fill<<<gE8, 256, 0, stream>>>(e_src, e_dst, ew, deg, cnt, ell, E);
    k_pad <<<(n * 8 + 255) / 256, 256, 0, stream>>>(cnt, ell, n);

    const int NB = (n + 63) / 64;           // one 64-row tile per block
    k_gemm<false><<<NB, 256, 0, stream>>>(x,     W1t, h16_a, n);
    k_agg<true, true> <<<(n + 3) / 4, 256, 0, stream>>>(h16_a, ell, cnt, deg, b1, h16_b, n);
    k_gemm<true> <<<NB, 256, 0, stream>>>(h16_b, W2t, h16_a, n);
    k_agg<false, false><<<(n + 3) / 4, 256, 0, stream>>>(h16_a, ell, cnt, deg, b2, hf, n);

    k_pool<<<128, 1024, 0, stream>>>(hf, bidx, gp, n);
    k_head<<<128, 128, 0, stream>>>(gp, l1W, l1b, gam, bet, l2W, l2b, out);
}

// Round 10
// 182.242 us; speedup vs baseline: 3.1104x; 1.0074x over previous
//
#include <hip/hip_runtime.h>
#include <hip/hip_bf16.h>

constexpr int MAXDEG = 64;

typedef __attribute__((ext_vector_type(8))) short short8;
typedef __attribute__((ext_vector_type(4))) float f32x4;

__device__ inline float bf_lo(unsigned u) { return __uint_as_float(u << 16); }
__device__ inline float bf_hi(unsigned u) { return __uint_as_float(u & 0xffff0000u); }
__device__ inline unsigned bf_pack(float a, float b) {
    __hip_bfloat162 t = __float22bfloat162_rn(make_float2(a, b));
    return *reinterpret_cast<unsigned*>(&t);
}
__device__ inline unsigned short bf1(float a) {
    __hip_bfloat16 t = __float2bfloat16(a);
    return *reinterpret_cast<unsigned short*>(&t);
}

// ---------------- init: W1t/W2t transpose-cast + zero deg/cnt (one dispatch) -
__global__ __launch_bounds__(256) void k_init(
    const float* __restrict__ W1, const float* __restrict__ W2,
    unsigned short* __restrict__ W1t, unsigned short* __restrict__ W2t,
    float* __restrict__ deg, int* __restrict__ cnt, int n)
{
    int idx = blockIdx.x * 256 + threadIdx.x;
    if (idx < 16384) {
        int k = idx >> 7, nn = idx & 127;
        W1t[nn * 128 + k] = bf1(W1[k * 128 + nn]);
        W2t[nn * 128 + k] = bf1(W2[k * 128 + nn]);
    }
    if (idx < n) { deg[idx] = 0.f; cnt[idx] = 0; }
}

// ---------------- single edge pass: deg atomics + slot assign + raw store ----
// Stores {src, raw_weight}; norm is patched in k_finish once deg is complete.
// 2 edges/thread -> ~1172 blocks: max wave parallelism for the atomic stream.
__global__ __launch_bounds__(256) void k_build(
    const int* __restrict__ src, const int* __restrict__ dst,
    const float* __restrict__ ew, float* __restrict__ deg,
    int* __restrict__ cnt, uint2* __restrict__ ell, int E)
{
    int e0 = (blockIdx.x * 256 + threadIdx.x) * 2;
    if (e0 + 1 < E) {
        const int2   s2 = *(const int2*)  &src[e0];
        const int2   d2 = *(const int2*)  &dst[e0];
        const float2 w2 = *(const float2*)&ew[e0];
        atomicAdd(&deg[d2.x], w2.x);
        atomicAdd(&deg[d2.y], w2.y);
        int sl0 = atomicAdd(&cnt[d2.x], 1);
        int sl1 = atomicAdd(&cnt[d2.y], 1);
        if (sl0 < MAXDEG) ell[d2.x * MAXDEG + sl0] = make_uint2((unsigned)s2.x, __float_as_uint(w2.x));
        if (sl1 < MAXDEG) ell[d2.y * MAXDEG + sl1] = make_uint2((unsigned)s2.y, __float_as_uint(w2.y));
    } else if (e0 < E) {
        int s = src[e0], d = dst[e0];
        float w = ew[e0];
        atomicAdd(&deg[d], w);
        int slot = atomicAdd(&cnt[d], 1);
        if (slot < MAXDEG) ell[d * MAXDEG + slot] = make_uint2((unsigned)s, __float_as_uint(w));
    }
}

// ---------------- finish: patch norms + zero pad slots (wave per node) -------
// 64 lanes = 64 ELL slots; coalesced 512B row RMW (L2-hot), 1 random dinv load
// per occupied slot. Absorbs the old k_pad.
__global__ __launch_bounds__(256) void k_finish(
    const float* __restrict__ deg, const int* __restrict__ cnt,
    uint2* __restrict__ ell, int n)
{
    const int lane = threadIdx.x & 63;
    const int wv   = threadIdx.x >> 6;
    const int i    = blockIdx.x * 4 + wv;
    if (i >= n) return;
    const int m  = min(cnt[i], MAXDEG);
    const int m8 = min((m + 7) & ~7, MAXDEG);
    if (lane >= m8) return;
    const float di = rsqrtf(deg[i] + 1.f);
    const size_t idx = (size_t)i * MAXDEG + lane;
    if (lane < m) {
        uint2 e = ell[idx];
        const float w  = __uint_as_float(e.y);
        const float nm = rsqrtf(deg[e.x] + 1.f) * w * di;
        ell[idx] = make_uint2(e.x, __float_as_uint(nm));
    } else {
        ell[idx] = make_uint2(0u, 0u);   // norm 0 => no-op in k_agg
    }
}

// ---------------- MFMA GEMM: C[n][128](bf16) = A[n][128] @ W ----------------
// Wt = W^T bf16 staged in LDS with XOR seg-swizzle (bank-conflict-free frags).
// 4 waves x 16 rows = 64 rows/block. Per wave: 8 col-tiles x 4 k-slices = 32
// mfma_f32_16x16x32_bf16. C/D layout (m89): col=lane&15, row=(lane>>4)*4+reg.
template <bool IN_BF16>
__global__ __launch_bounds__(256, 4) void k_gemm(
    const void* __restrict__ Ain, const unsigned short* __restrict__ Wt,
    unsigned short* __restrict__ C, int n)
{
    __shared__ unsigned short Ws[128 * 128];    // 32 KB
    {   // stage Wt: 2048 uint4; swizzle seg^(row&7) in 16B units
        const uint4* Wv = (const uint4*)Wt;
        uint4* Sv = (uint4*)Ws;
        #pragma unroll
        for (int i = threadIdx.x; i < 2048; i += 256) {
            int row = i >> 4, seg = i & 15;
            Sv[row * 16 + (seg ^ (row & 7))] = Wv[i];
        }
    }
    __syncthreads();

    const float*          Af = (const float*)Ain;
    const unsigned short* Ab = (const unsigned short*)Ain;

    const int wid  = threadIdx.x >> 6;          // 0..3
    const int lane = threadIdx.x & 63;
    const int r    = lane & 15;
    const int kg   = lane >> 4;                 // 0..3
    const int m0   = blockIdx.x * 64 + wid * 16;
    const size_t arow = (size_t)min(m0 + r, n - 1) * 128;

    f32x4 acc[8];
    #pragma unroll
    for (int ct = 0; ct < 8; ++ct) acc[ct] = (f32x4){0.f, 0.f, 0.f, 0.f};

    const short8* Ws8 = (const short8*)Ws;

    #pragma unroll
    for (int ks = 0; ks < 4; ++ks) {
        const int k0 = ks * 32 + kg * 8;
        short8 afrag;
        if constexpr (IN_BF16) {
            afrag = *(const short8*)(Ab + arow + k0);
        } else {
            const float4 lo = *(const float4*)(Af + arow + k0);
            const float4 hi = *(const float4*)(Af + arow + k0 + 4);
            union { short8 s; uint4 u; } cvt;
            cvt.u = make_uint4(bf_pack(lo.x, lo.y), bf_pack(lo.z, lo.w),
                               bf_pack(hi.x, hi.y), bf_pack(hi.z, hi.w));
            afrag = cvt.s;
        }
        const int segi = ks * 4 + kg;
        #pragma unroll
        for (int ct = 0; ct < 8; ++ct) {
            const int ncol = ct * 16 + r;
            const short8 bfrag = Ws8[ncol * 16 + (segi ^ (ncol & 7))];
            acc[ct] = __builtin_amdgcn_mfma_f32_16x16x32_bf16(afrag, bfrag, acc[ct], 0, 0, 0);
        }
    }

    #pragma unroll
    for (int ct = 0; ct < 8; ++ct) {
        #pragma unroll
        for (int reg = 0; reg < 4; ++reg) {
            const int row = m0 + kg * 4 + reg;
            if (row < n) C[(size_t)row * 128 + ct * 16 + r] = bf1(acc[ct][reg]);
        }
    }
}

// ---------------- aggregation over bf16 h, f32 accumulate --------------------
template <bool RELU, bool OUT_BF16>
__global__ __launch_bounds__(256) void k_agg(
    const unsigned short* __restrict__ h, const uint2* __restrict__ ell,
    const int* __restrict__ cnt, const float* __restrict__ deg,
    const float* __restrict__ bias, void* __restrict__ outv, int n)
{
    const int lane = threadIdx.x & 63;
    const int wv   = threadIdx.x >> 6;
    const int i    = blockIdx.x * 4 + wv;
    if (i >= n) return;
    const int f = lane * 2;
    float ax = 0.f, ay = 0.f;
    const int m    = min(cnt[i], MAXDEG);
    const int m8   = min((m + 7) & ~7, MAXDEG);
    const int base = i * MAXDEG;
    for (int j = 0; j < m8; j += 8) {
        const uint4 p0 = *(const uint4*)&ell[base + j];      // entries j, j+1
        const uint4 p1 = *(const uint4*)&ell[base + j + 2];
        const uint4 p2 = *(const uint4*)&ell[base + j + 4];
        const uint4 p3 = *(const uint4*)&ell[base + j + 6];
        const unsigned g0 = *(const unsigned*)&h[(size_t)p0.x * 128 + f];
        const unsigned g1 = *(const unsigned*)&h[(size_t)p0.z * 128 + f];
        const unsigned g2 = *(const unsigned*)&h[(size_t)p1.x * 128 + f];
        const unsigned g3 = *(const unsigned*)&h[(size_t)p1.z * 128 + f];
        const unsigned g4 = *(const unsigned*)&h[(size_t)p2.x * 128 + f];
        const unsigned g5 = *(const unsigned*)&h[(size_t)p2.z * 128 + f];
        const unsigned g6 = *(const unsigned*)&h[(size_t)p3.x * 128 + f];
        const unsigned g7 = *(const unsigned*)&h[(size_t)p3.z * 128 + f];
        const float w0 = __uint_as_float(p0.y), w1 = __uint_as_float(p0.w);
        const float w2 = __uint_as_float(p1.y), w3 = __uint_as_float(p1.w);
        const float w4 = __uint_as_float(p2.y), w5 = __uint_as_float(p2.w);
        const float w6 = __uint_as_float(p3.y), w7 = __uint_as_float(p3.w);
        ax = fmaf(w0, bf_lo(g0), ax); ay = fmaf(w0, bf_hi(g0), ay);
        ax = fmaf(w1, bf_lo(g1), ax); ay = fmaf(w1, bf_hi(g1), ay);
        ax = fmaf(w2, bf_lo(g2), ax); ay = fmaf(w2, bf_hi(g2), ay);
        ax = fmaf(w3, bf_lo(g3), ax); ay = fmaf(w3, bf_hi(g3), ay);
        ax = fmaf(w4, bf_lo(g4), ax); ay = fmaf(w4, bf_hi(g4), ay);
        ax = fmaf(w5, bf_lo(g5), ax); ay = fmaf(w5, bf_hi(g5), ay);
        ax = fmaf(w6, bf_lo(g6), ax); ay = fmaf(w6, bf_hi(g6), ay);
        ax = fmaf(w7, bf_lo(g7), ax); ay = fmaf(w7, bf_hi(g7), ay);
    }
    const float di = rsqrtf(deg[i] + 1.f);
    const float wl = di * di;
    const unsigned hs = *(const unsigned*)&h[(size_t)i * 128 + f];
    ax = fmaf(wl, bf_lo(hs), ax);
    ay = fmaf(wl, bf_hi(hs), ay);
    const float2 bb = *(const float2*)&bias[f];
    ax += bb.x; ay += bb.y;
    if (RELU) { ax = fmaxf(ax, 0.f); ay = fmaxf(ay, 0.f); }
    if constexpr (OUT_BF16) {
        ((unsigned*)outv)[((size_t)i * 128 + f) >> 1] = bf_pack(ax, ay);
    } else {
        float2 o; o.x = ax; o.y = ay;
        *(float2*)&((float*)outv)[(size_t)i * 128 + f] = o;
    }
}

// ---------------- mean pool per graph: 1024 threads = 16 waves --------------
__global__ __launch_bounds__(1024) void k_pool(
    const float* __restrict__ h, const int* __restrict__ batch,
    float* __restrict__ gout, int n)
{
    const int gi   = blockIdx.x;
    const int lane = threadIdx.x & 63;
    const int wv   = threadIdx.x >> 6;        // 0..15
    __shared__ int sse[2];
    __shared__ float red[16 * 128];
    if (threadIdx.x < 2) {
        const int target = gi + (int)threadIdx.x;
        int lo = 0, hi = n;
        while (lo < hi) { int m = (lo + hi) >> 1; if (batch[m] < target) lo = m + 1; else hi = m; }
        sse[threadIdx.x] = lo;
    }
    __syncthreads();
    const int ss = sse[0], se = sse[1];
    const int f = lane * 2;
    float ax = 0.f, ay = 0.f;
    for (int i = ss + wv; i < se; i += 16) {
        const float2 hv = *(const float2*)&h[(size_t)i * 128 + f];
        ax += hv.x; ay += hv.y;
    }
    red[wv * 128 + f]     = ax;
    red[wv * 128 + f + 1] = ay;
    __syncthreads();
    if (threadIdx.x < 128) {
        const int t = threadIdx.x;
        float acc = 0.f;
        #pragma unroll
        for (int j = 0; j < 16; ++j) acc += red[j * 128 + t];
        const float c = (float)(se - ss);
        gout[gi * 128 + t] = acc / fmaxf(c, 1.f);
    }
}

// ---------------- fused head: Linear->ReLU->LayerNorm->Linear ----------------
__global__ __launch_bounds__(128) void k_head(
    const float* __restrict__ g, const float* __restrict__ l1W,
    const float* __restrict__ l1b, const float* __restrict__ gamma,
    const float* __restrict__ beta, const float* __restrict__ l2W,
    const float* __restrict__ l2b, float* __restrict__ out)
{
    const int gi = blockIdx.x;
    const int t  = threadIdx.x;      // 128 threads
    __shared__ float gs[128], zs[128], red[128];
    gs[t] = g[gi * 128 + t];
    __syncthreads();
    float acc = l1b[t];
    for (int k = 0; k < 128; ++k) acc = fmaf(gs[k], l1W[k * 128 + t], acc);
    acc = fmaxf(acc, 0.f);
    red[t] = acc; __syncthreads();
    for (int off = 64; off > 0; off >>= 1) {
        if (t < off) red[t] += red[t + off];
        __syncthreads();
    }
    const float mu = red[0] * (1.f / 128.f);
    __syncthreads();
    const float d = acc - mu;
    red[t] = d * d; __syncthreads();
    for (int off = 64; off > 0; off >>= 1) {
        if (t < off) red[t] += red[t + off];
        __syncthreads();
    }
    const float var = red[0] * (1.f / 128.f);
    const float z = (acc - mu) * rsqrtf(var + 1e-5f) * gamma[t] + beta[t];
    zs[t] = z;
    __syncthreads();
    if (t < 16) {
        float o = l2b[t];
        for (int k = 0; k < 128; ++k) o = fmaf(zs[k], l2W[k * 16 + t], o);
        out[gi * 16 + t] = o;
    }
}

extern "C" void kernel_launch(void* const* d_in, const int* in_sizes, int n_in,
                              void* d_out, int out_size, void* d_ws, size_t ws_size,
                              hipStream_t stream)
{
    const float* x    = (const float*)d_in[0];
    const int*   ei   = (const int*)  d_in[1];
    const float* ew   = (const float*)d_in[2];
    const int*   bidx = (const int*)  d_in[3];
    const float* W1   = (const float*)d_in[4];
    const float* b1   = (const float*)d_in[5];
    const float* W2   = (const float*)d_in[6];
    const float* b2   = (const float*)d_in[7];
    const float* l1W  = (const float*)d_in[8];
    const float* l1b  = (const float*)d_in[9];
    const float* gam  = (const float*)d_in[10];
    const float* bet  = (const float*)d_in[11];
    const float* l2W  = (const float*)d_in[12];
    const float* l2b  = (const float*)d_in[13];
    float* out = (float*)d_out;

    const int E = in_sizes[2];              // edge_weight count
    const int n = in_sizes[3];              // batch_idx count = N nodes
    const int* e_src = ei;                  // edge_index[0]
    const int* e_dst = ei + E;              // edge_index[1]

    char* p = (char*)d_ws;
    auto alloc = [&](size_t bytes) { char* r = p; p += (bytes + 255) & ~(size_t)255; return r; };
    unsigned short* h16_a = (unsigned short*)alloc((size_t)n * 128 * 2);  // gemm1 out / gemm2 out
    unsigned short* h16_b = (unsigned short*)alloc((size_t)n * 128 * 2);  // agg1 out (relu'd)
    float* hf    = (float*)alloc((size_t)n * 128 * 4);                    // agg2 out (f32)
    uint2* ell   = (uint2*)alloc((size_t)n * MAXDEG * 8);
    float* deg   = (float*)alloc((size_t)n * 4);
    int*   cnt   = (int*)  alloc((size_t)n * 4);
    float* gp    = (float*)alloc((size_t)128 * 128 * 4);
    unsigned short* W1t = (unsigned short*)alloc((size_t)128 * 128 * 2);
    unsigned short* W2t = (unsigned short*)alloc((size_t)128 * 128 * 2);

    const int initWork = (n > 16384 ? n : 16384);
    k_init<<<(initWork + 255) / 256, 256, 0, stream>>>(W1, W2, W1t, W2t, deg, cnt, n);

    const int gE2 = (E / 2 + 255) / 256 + 1;
    k_build <<<gE2, 256, 0, stream>>>(e_src, e_dst, ew, deg, cnt, ell, E);
    k_finish<<<(n + 3) / 4, 256, 0, stream>>>(deg, cnt, ell, n);

    const int NB = (n + 63) / 64;           // one 64-row tile per block
    k_gemm<false><<<NB, 256, 0, stream>>>(x,     W1t, h16_a, n);
    k_agg<true, true> <<<(n + 3) / 4, 256, 0, stream>>>(h16_a, ell, cnt, deg, b1, h16_b, n);
    k_gemm<true> <<<NB, 256, 0, stream>>>(h16_b, W2t, h16_a, n);
    k_agg<false, false><<<(n + 3) / 4, 256, 0, stream>>>(h16_a, ell, cnt, deg, b2, hf, n);

    k_pool<<<128, 1024, 0, stream>>>(hf, bidx, gp, n);
    k_head<<<128, 128, 0, stream>>>(gp, l1W, l1b, gam, bet, l2W, l2b, out);
}

// Round 11
// 159.043 us; speedup vs baseline: 3.5641x; 1.1459x over previous
//
#include <hip/hip_runtime.h>
#include <hip/hip_bf16.h>

constexpr int MAXDEG = 64;

typedef __attribute__((ext_vector_type(8))) short short8;
typedef __attribute__((ext_vector_type(4))) float f32x4;

__device__ inline float bf_lo(unsigned u) { return __uint_as_float(u << 16); }
__device__ inline float bf_hi(unsigned u) { return __uint_as_float(u & 0xffff0000u); }
__device__ inline unsigned bf_pack(float a, float b) {
    __hip_bfloat162 t = __float22bfloat162_rn(make_float2(a, b));
    return *reinterpret_cast<unsigned*>(&t);
}
__device__ inline unsigned short bf1(float a) {
    __hip_bfloat16 t = __float2bfloat16(a);
    return *reinterpret_cast<unsigned short*>(&t);
}

// ---------------- init: W1t/W2t transpose-cast + zero cnt (one dispatch) -----
__global__ __launch_bounds__(256) void k_init(
    const float* __restrict__ W1, const float* __restrict__ W2,
    unsigned short* __restrict__ W1t, unsigned short* __restrict__ W2t,
    int* __restrict__ cnt, int n)
{
    int idx = blockIdx.x * 256 + threadIdx.x;
    if (idx < 16384) {
        int k = idx >> 7, nn = idx & 127;
        W1t[nn * 128 + k] = bf1(W1[k * 128 + nn]);
        W2t[nn * 128 + k] = bf1(W2[k * 128 + nn]);
    }
    if (idx < n) cnt[idx] = 0;
}

// ---------------- edge pass: slot atomic + raw {src,w} scatter, 8/thread -----
// No deg atomics: deg is reduced from the ELL rows afterwards (k_degsum).
__global__ __launch_bounds__(256) void k_build(
    const int* __restrict__ src, const int* __restrict__ dst,
    const float* __restrict__ ew, int* __restrict__ cnt,
    uint2* __restrict__ ell, int E)
{
    int e0 = (blockIdx.x * 256 + threadIdx.x) * 8;
    if (e0 + 7 < E) {
        const int4   sa = *(const int4*)  &src[e0];
        const int4   sb = *(const int4*)  &src[e0 + 4];
        const int4   da = *(const int4*)  &dst[e0];
        const int4   db = *(const int4*)  &dst[e0 + 4];
        const float4 wa = *(const float4*)&ew[e0];
        const float4 wb = *(const float4*)&ew[e0 + 4];
        int sl0 = atomicAdd(&cnt[da.x], 1);
        int sl1 = atomicAdd(&cnt[da.y], 1);
        int sl2 = atomicAdd(&cnt[da.z], 1);
        int sl3 = atomicAdd(&cnt[da.w], 1);
        int sl4 = atomicAdd(&cnt[db.x], 1);
        int sl5 = atomicAdd(&cnt[db.y], 1);
        int sl6 = atomicAdd(&cnt[db.z], 1);
        int sl7 = atomicAdd(&cnt[db.w], 1);
        if (sl0 < MAXDEG) ell[da.x * MAXDEG + sl0] = make_uint2((unsigned)sa.x, __float_as_uint(wa.x));
        if (sl1 < MAXDEG) ell[da.y * MAXDEG + sl1] = make_uint2((unsigned)sa.y, __float_as_uint(wa.y));
        if (sl2 < MAXDEG) ell[da.z * MAXDEG + sl2] = make_uint2((unsigned)sa.z, __float_as_uint(wa.z));
        if (sl3 < MAXDEG) ell[da.w * MAXDEG + sl3] = make_uint2((unsigned)sa.w, __float_as_uint(wa.w));
        if (sl4 < MAXDEG) ell[db.x * MAXDEG + sl4] = make_uint2((unsigned)sb.x, __float_as_uint(wb.x));
        if (sl5 < MAXDEG) ell[db.y * MAXDEG + sl5] = make_uint2((unsigned)sb.y, __float_as_uint(wb.y));
        if (sl6 < MAXDEG) ell[db.z * MAXDEG + sl6] = make_uint2((unsigned)sb.z, __float_as_uint(wb.z));
        if (sl7 < MAXDEG) ell[db.w * MAXDEG + sl7] = make_uint2((unsigned)sb.w, __float_as_uint(wb.w));
    } else {
        for (int e = e0; e < E; ++e) {
            int s = src[e], d = dst[e];
            float w = ew[e];
            int slot = atomicAdd(&cnt[d], 1);
            if (slot < MAXDEG) ell[d * MAXDEG + slot] = make_uint2((unsigned)s, __float_as_uint(w));
        }
    }
}

// ---------------- deg[i] = sum of raw weights in row i (coalesced, L2-hot) ---
// wave per node; also zeroes the pad slots up to the next multiple of 8.
__global__ __launch_bounds__(256) void k_degsum(
    const int* __restrict__ cnt, uint2* __restrict__ ell,
    float* __restrict__ deg, int n)
{
    const int lane = threadIdx.x & 63;
    const int wv   = threadIdx.x >> 6;
    const int i    = blockIdx.x * 4 + wv;
    if (i >= n) return;
    const int m  = min(cnt[i], MAXDEG);
    const int m8 = min((m + 7) & ~7, MAXDEG);
    const size_t idx = (size_t)i * MAXDEG + lane;
    float w = 0.f;
    if (lane < m) {
        w = __uint_as_float(ell[idx].y);
    } else if (lane < m8) {
        ell[idx] = make_uint2(0u, 0u);   // pad: norm 0 => no-op in k_agg
    }
    #pragma unroll
    for (int off = 32; off > 0; off >>= 1) w += __shfl_xor(w, off);
    if (lane == 0) deg[i] = w;
}

// ---------------- patch norms: ell[i][j].w = dinv[src]*w*dinv[i] -------------
__global__ __launch_bounds__(256) void k_norm(
    const float* __restrict__ deg, const int* __restrict__ cnt,
    uint2* __restrict__ ell, int n)
{
    const int lane = threadIdx.x & 63;
    const int wv   = threadIdx.x >> 6;
    const int i    = blockIdx.x * 4 + wv;
    if (i >= n) return;
    const int m = min(cnt[i], MAXDEG);
    if (lane >= m) return;
    const float di = rsqrtf(deg[i] + 1.f);
    const size_t idx = (size_t)i * MAXDEG + lane;
    uint2 e = ell[idx];
    const float nm = rsqrtf(deg[e.x] + 1.f) * __uint_as_float(e.y) * di;
    ell[idx] = make_uint2(e.x, __float_as_uint(nm));
}

// ---------------- MFMA GEMM: C[n][128](bf16) = A[n][128] @ W ----------------
// Wt = W^T bf16 staged in LDS with XOR seg-swizzle (bank-conflict-free frags).
// 4 waves x 16 rows = 64 rows/block. Per wave: 8 col-tiles x 4 k-slices = 32
// mfma_f32_16x16x32_bf16. C/D layout (m89): col=lane&15, row=(lane>>4)*4+reg.
template <bool IN_BF16>
__global__ __launch_bounds__(256, 4) void k_gemm(
    const void* __restrict__ Ain, const unsigned short* __restrict__ Wt,
    unsigned short* __restrict__ C, int n)
{
    __shared__ unsigned short Ws[128 * 128];    // 32 KB
    {   // stage Wt: 2048 uint4; swizzle seg^(row&7) in 16B units
        const uint4* Wv = (const uint4*)Wt;
        uint4* Sv = (uint4*)Ws;
        #pragma unroll
        for (int i = threadIdx.x; i < 2048; i += 256) {
            int row = i >> 4, seg = i & 15;
            Sv[row * 16 + (seg ^ (row & 7))] = Wv[i];
        }
    }
    __syncthreads();

    const float*          Af = (const float*)Ain;
    const unsigned short* Ab = (const unsigned short*)Ain;

    const int wid  = threadIdx.x >> 6;          // 0..3
    const int lane = threadIdx.x & 63;
    const int r    = lane & 15;
    const int kg   = lane >> 4;                 // 0..3
    const int m0   = blockIdx.x * 64 + wid * 16;
    const size_t arow = (size_t)min(m0 + r, n - 1) * 128;

    f32x4 acc[8];
    #pragma unroll
    for (int ct = 0; ct < 8; ++ct) acc[ct] = (f32x4){0.f, 0.f, 0.f, 0.f};

    const short8* Ws8 = (const short8*)Ws;

    #pragma unroll
    for (int ks = 0; ks < 4; ++ks) {
        const int k0 = ks * 32 + kg * 8;
        short8 afrag;
        if constexpr (IN_BF16) {
            afrag = *(const short8*)(Ab + arow + k0);
        } else {
            const float4 lo = *(const float4*)(Af + arow + k0);
            const float4 hi = *(const float4*)(Af + arow + k0 + 4);
            union { short8 s; uint4 u; } cvt;
            cvt.u = make_uint4(bf_pack(lo.x, lo.y), bf_pack(lo.z, lo.w),
                               bf_pack(hi.x, hi.y), bf_pack(hi.z, hi.w));
            afrag = cvt.s;
        }
        const int segi = ks * 4 + kg;
        #pragma unroll
        for (int ct = 0; ct < 8; ++ct) {
            const int ncol = ct * 16 + r;
            const short8 bfrag = Ws8[ncol * 16 + (segi ^ (ncol & 7))];
            acc[ct] = __builtin_amdgcn_mfma_f32_16x16x32_bf16(afrag, bfrag, acc[ct], 0, 0, 0);
        }
    }

    #pragma unroll
    for (int ct = 0; ct < 8; ++ct) {
        #pragma unroll
        for (int reg = 0; reg < 4; ++reg) {
            const int row = m0 + kg * 4 + reg;
            if (row < n) C[(size_t)row * 128 + ct * 16 + r] = bf1(acc[ct][reg]);
        }
    }
}

// ---------------- aggregation over bf16 h, f32 accumulate --------------------
template <bool RELU, bool OUT_BF16>
__global__ __launch_bounds__(256) void k_agg(
    const unsigned short* __restrict__ h, const uint2* __restrict__ ell,
    const int* __restrict__ cnt, const float* __restrict__ deg,
    const float* __restrict__ bias, void* __restrict__ outv, int n)
{
    const int lane = threadIdx.x & 63;
    const int wv   = threadIdx.x >> 6;
    const int i    = blockIdx.x * 4 + wv;
    if (i >= n) return;
    const int f = lane * 2;
    float ax = 0.f, ay = 0.f;
    const int m    = min(cnt[i], MAXDEG);
    const int m8   = min((m + 7) & ~7, MAXDEG);
    const int base = i * MAXDEG;
    for (int j = 0; j < m8; j += 8) {
        const uint4 p0 = *(const uint4*)&ell[base + j];      // entries j, j+1
        const uint4 p1 = *(const uint4*)&ell[base + j + 2];
        const uint4 p2 = *(const uint4*)&ell[base + j + 4];
        const uint4 p3 = *(const uint4*)&ell[base + j + 6];
        const unsigned g0 = *(const unsigned*)&h[(size_t)p0.x * 128 + f];
        const unsigned g1 = *(const unsigned*)&h[(size_t)p0.z * 128 + f];
        const unsigned g2 = *(const unsigned*)&h[(size_t)p1.x * 128 + f];
        const unsigned g3 = *(const unsigned*)&h[(size_t)p1.z * 128 + f];
        const unsigned g4 = *(const unsigned*)&h[(size_t)p2.x * 128 + f];
        const unsigned g5 = *(const unsigned*)&h[(size_t)p2.z * 128 + f];
        const unsigned g6 = *(const unsigned*)&h[(size_t)p3.x * 128 + f];
        const unsigned g7 = *(const unsigned*)&h[(size_t)p3.z * 128 + f];
        const float w0 = __uint_as_float(p0.y), w1 = __uint_as_float(p0.w);
        const float w2 = __uint_as_float(p1.y), w3 = __uint_as_float(p1.w);
        const float w4 = __uint_as_float(p2.y), w5 = __uint_as_float(p2.w);
        const float w6 = __uint_as_float(p3.y), w7 = __uint_as_float(p3.w);
        ax = fmaf(w0, bf_lo(g0), ax); ay = fmaf(w0, bf_hi(g0), ay);
        ax = fmaf(w1, bf_lo(g1), ax); ay = fmaf(w1, bf_hi(g1), ay);
        ax = fmaf(w2, bf_lo(g2), ax); ay = fmaf(w2, bf_hi(g2), ay);
        ax = fmaf(w3, bf_lo(g3), ax); ay = fmaf(w3, bf_hi(g3), ay);
        ax = fmaf(w4, bf_lo(g4), ax); ay = fmaf(w4, bf_hi(g4), ay);
        ax = fmaf(w5, bf_lo(g5), ax); ay = fmaf(w5, bf_hi(g5), ay);
        ax = fmaf(w6, bf_lo(g6), ax); ay = fmaf(w6, bf_hi(g6), ay);
        ax = fmaf(w7, bf_lo(g7), ax); ay = fmaf(w7, bf_hi(g7), ay);
    }
    const float di = rsqrtf(deg[i] + 1.f);
    const float wl = di * di;
    const unsigned hs = *(const unsigned*)&h[(size_t)i * 128 + f];
    ax = fmaf(wl, bf_lo(hs), ax);
    ay = fmaf(wl, bf_hi(hs), ay);
    const float2 bb = *(const float2*)&bias[f];
    ax += bb.x; ay += bb.y;
    if (RELU) { ax = fmaxf(ax, 0.f); ay = fmaxf(ay, 0.f); }
    if constexpr (OUT_BF16) {
        ((unsigned*)outv)[((size_t)i * 128 + f) >> 1] = bf_pack(ax, ay);
    } else {
        float2 o; o.x = ax; o.y = ay;
        *(float2*)&((float*)outv)[(size_t)i * 128 + f] = o;
    }
}

// ---------------- mean pool per graph: 1024 threads = 16 waves --------------
__global__ __launch_bounds__(1024) void k_pool(
    const float* __restrict__ h, const int* __restrict__ batch,
    float* __restrict__ gout, int n)
{
    const int gi   = blockIdx.x;
    const int lane = threadIdx.x & 63;
    const int wv   = threadIdx.x >> 6;        // 0..15
    __shared__ int sse[2];
    __shared__ float red[16 * 128];
    if (threadIdx.x < 2) {
        const int target = gi + (int)threadIdx.x;
        int lo = 0, hi = n;
        while (lo < hi) { int m = (lo + hi) >> 1; if (batch[m] < target) lo = m + 1; else hi = m; }
        sse[threadIdx.x] = lo;
    }
    __syncthreads();
    const int ss = sse[0], se = sse[1];
    const int f = lane * 2;
    float ax = 0.f, ay = 0.f;
    for (int i = ss + wv; i < se; i += 16) {
        const float2 hv = *(const float2*)&h[(size_t)i * 128 + f];
        ax += hv.x; ay += hv.y;
    }
    red[wv * 128 + f]     = ax;
    red[wv * 128 + f + 1] = ay;
    __syncthreads();
    if (threadIdx.x < 128) {
        const int t = threadIdx.x;
        float acc = 0.f;
        #pragma unroll
        for (int j = 0; j < 16; ++j) acc += red[j * 128 + t];
        const float c = (float)(se - ss);
        gout[gi * 128 + t] = acc / fmaxf(c, 1.f);
    }
}

// ---------------- fused head: Linear->ReLU->LayerNorm->Linear ----------------
__global__ __launch_bounds__(128) void k_head(
    const float* __restrict__ g, const float* __restrict__ l1W,
    const float* __restrict__ l1b, const float* __restrict__ gamma,
    const float* __restrict__ beta, const float* __restrict__ l2W,
    const float* __restrict__ l2b, float* __restrict__ out)
{
    const int gi = blockIdx.x;
    const int t  = threadIdx.x;      // 128 threads
    __shared__ float gs[128], zs[128], red[128];
    gs[t] = g[gi * 128 + t];
    __syncthreads();
    float acc = l1b[t];
    for (int k = 0; k < 128; ++k) acc = fmaf(gs[k], l1W[k * 128 + t], acc);
    acc = fmaxf(acc, 0.f);
    red[t] = acc; __syncthreads();
    for (int off = 64; off > 0; off >>= 1) {
        if (t < off) red[t] += red[t + off];
        __syncthreads();
    }
    const float mu = red[0] * (1.f / 128.f);
    __syncthreads();
    const float d = acc - mu;
    red[t] = d * d; __syncthreads();
    for (int off = 64; off > 0; off >>= 1) {
        if (t < off) red[t] += red[t + off];
        __syncthreads();
    }
    const float var = red[0] * (1.f / 128.f);
    const float z = (acc - mu) * rsqrtf(var + 1e-5f) * gamma[t] + beta[t];
    zs[t] = z;
    __syncthreads();
    if (t < 16) {
        float o = l2b[t];
        for (int k = 0; k < 128; ++k) o = fmaf(zs[k], l2W[k * 16 + t], o);
        out[gi * 16 + t] = o;
    }
}

extern "C" void kernel_launch(void* const* d_in, const int* in_sizes, int n_in,
                              void* d_out, int out_size, void* d_ws, size_t ws_size,
                              hipStream_t stream)
{
    const float* x    = (const float*)d_in[0];
    const int*   ei   = (const int*)  d_in[1];
    const float* ew   = (const float*)d_in[2];
    const int*   bidx = (const int*)  d_in[3];
    const float* W1   = (const float*)d_in[4];
    const float* b1   = (const float*)d_in[5];
    const float* W2   = (const float*)d_in[6];
    const float* b2   = (const float*)d_in[7];
    const float* l1W  = (const float*)d_in[8];
    const float* l1b  = (const float*)d_in[9];
    const float* gam  = (const float*)d_in[10];
    const float* bet  = (const float*)d_in[11];
    const float* l2W  = (const float*)d_in[12];
    const float* l2b  = (const float*)d_in[13];
    float* out = (float*)d_out;

    const int E = in_sizes[2];              // edge_weight count
    const int n = in_sizes[3];              // batch_idx count = N nodes
    const int* e_src = ei;                  // edge_index[0]
    const int* e_dst = ei + E;              // edge_index[1]

    char* p = (char*)d_ws;
    auto alloc = [&](size_t bytes) { char* r = p; p += (bytes + 255) & ~(size_t)255; return r; };
    unsigned short* h16_a = (unsigned short*)alloc((size_t)n * 128 * 2);  // gemm1 out / gemm2 out
    unsigned short* h16_b = (unsigned short*)alloc((size_t)n * 128 * 2);  // agg1 out (relu'd)
    float* hf    = (float*)alloc((size_t)n * 128 * 4);                    // agg2 out (f32)
    uint2* ell   = (uint2*)alloc((size_t)n * MAXDEG * 8);
    float* deg   = (float*)alloc((size_t)n * 4);
    int*   cnt   = (int*)  alloc((size_t)n * 4);
    float* gp    = (float*)alloc((size_t)128 * 128 * 4);
    unsigned short* W1t = (unsigned short*)alloc((size_t)128 * 128 * 2);
    unsigned short* W2t = (unsigned short*)alloc((size_t)128 * 128 * 2);

    const int initWork = (n > 16384 ? n : 16384);
    k_init<<<(initWork + 255) / 256, 256, 0, stream>>>(W1, W2, W1t, W2t, cnt, n);

    const int gE8 = (E / 8 + 255) / 256 + 1;
    k_build <<<gE8, 256, 0, stream>>>(e_src, e_dst, ew, cnt, ell, E);
    k_degsum<<<(n + 3) / 4, 256, 0, stream>>>(cnt, ell, deg, n);
    k_norm  <<<(n + 3) / 4, 256, 0, stream>>>(deg, cnt, ell, n);

    const int NB = (n + 63) / 64;           // one 64-row tile per block
    k_gemm<false><<<NB, 256, 0, stream>>>(x,     W1t, h16_a, n);
    k_agg<true, true> <<<(n + 3) / 4, 256, 0, stream>>>(h16_a, ell, cnt, deg, b1, h16_b, n);
    k_gemm<true> <<<NB, 256, 0, stream>>>(h16_b, W2t, h16_a, n);
    k_agg<false, false><<<(n + 3) / 4, 256, 0, stream>>>(h16_a, ell, cnt, deg, b2, hf, n);

    k_pool<<<128, 1024, 0, stream>>>(hf, bidx, gp, n);
    k_head<<<128, 128, 0, stream>>>(gp, l1W, l1b, gam, bet, l2W, l2b, out);
}

// Round 12
// 155.214 us; speedup vs baseline: 3.6521x; 1.0247x over previous
//
#include <hip/hip_runtime.h>
#include <hip/hip_bf16.h>

constexpr int MAXDEG = 64;
constexpr int CSTR   = 16;   // cnt padded to one 64B line per node (false-sharing fix)

typedef __attribute__((ext_vector_type(8))) short short8;
typedef __attribute__((ext_vector_type(4))) float f32x4;

__device__ inline float bf_lo(unsigned u) { return __uint_as_float(u << 16); }
__device__ inline float bf_hi(unsigned u) { return __uint_as_float(u & 0xffff0000u); }
__device__ inline unsigned bf_pack(float a, float b) {
    __hip_bfloat162 t = __float22bfloat162_rn(make_float2(a, b));
    return *reinterpret_cast<unsigned*>(&t);
}
__device__ inline unsigned short bf1(float a) {
    __hip_bfloat16 t = __float2bfloat16(a);
    return *reinterpret_cast<unsigned short*>(&t);
}

// ---------------- init: W1t/W2t transpose-cast + zero cnt (one dispatch) -----
__global__ __launch_bounds__(256) void k_init(
    const float* __restrict__ W1, const float* __restrict__ W2,
    unsigned short* __restrict__ W1t, unsigned short* __restrict__ W2t,
    int* __restrict__ cnt, int n)
{
    int idx = blockIdx.x * 256 + threadIdx.x;
    if (idx < 16384) {
        int k = idx >> 7, nn = idx & 127;
        W1t[nn * 128 + k] = bf1(W1[k * 128 + nn]);
        W2t[nn * 128 + k] = bf1(W2[k * 128 + nn]);
    }
    if (idx < n) cnt[(size_t)idx * CSTR] = 0;
}

// ---------------- edge pass: slot atomic + raw {src,w} scatter, 8/thread -----
__global__ __launch_bounds__(256) void k_build(
    const int* __restrict__ src, const int* __restrict__ dst,
    const float* __restrict__ ew, int* __restrict__ cnt,
    uint2* __restrict__ ell, int E)
{
    int e0 = (blockIdx.x * 256 + threadIdx.x) * 8;
    if (e0 + 7 < E) {
        const int4   sa = *(const int4*)  &src[e0];
        const int4   sb = *(const int4*)  &src[e0 + 4];
        const int4   da = *(const int4*)  &dst[e0];
        const int4   db = *(const int4*)  &dst[e0 + 4];
        const float4 wa = *(const float4*)&ew[e0];
        const float4 wb = *(const float4*)&ew[e0 + 4];
        int sl0 = atomicAdd(&cnt[(size_t)da.x * CSTR], 1);
        int sl1 = atomicAdd(&cnt[(size_t)da.y * CSTR], 1);
        int sl2 = atomicAdd(&cnt[(size_t)da.z * CSTR], 1);
        int sl3 = atomicAdd(&cnt[(size_t)da.w * CSTR], 1);
        int sl4 = atomicAdd(&cnt[(size_t)db.x * CSTR], 1);
        int sl5 = atomicAdd(&cnt[(size_t)db.y * CSTR], 1);
        int sl6 = atomicAdd(&cnt[(size_t)db.z * CSTR], 1);
        int sl7 = atomicAdd(&cnt[(size_t)db.w * CSTR], 1);
        if (sl0 < MAXDEG) ell[da.x * MAXDEG + sl0] = make_uint2((unsigned)sa.x, __float_as_uint(wa.x));
        if (sl1 < MAXDEG) ell[da.y * MAXDEG + sl1] = make_uint2((unsigned)sa.y, __float_as_uint(wa.y));
        if (sl2 < MAXDEG) ell[da.z * MAXDEG + sl2] = make_uint2((unsigned)sa.z, __float_as_uint(wa.z));
        if (sl3 < MAXDEG) ell[da.w * MAXDEG + sl3] = make_uint2((unsigned)sa.w, __float_as_uint(wa.w));
        if (sl4 < MAXDEG) ell[db.x * MAXDEG + sl4] = make_uint2((unsigned)sb.x, __float_as_uint(wb.x));
        if (sl5 < MAXDEG) ell[db.y * MAXDEG + sl5] = make_uint2((unsigned)sb.y, __float_as_uint(wb.y));
        if (sl6 < MAXDEG) ell[db.z * MAXDEG + sl6] = make_uint2((unsigned)sb.z, __float_as_uint(wb.z));
        if (sl7 < MAXDEG) ell[db.w * MAXDEG + sl7] = make_uint2((unsigned)sb.w, __float_as_uint(wb.w));
    } else {
        for (int e = e0; e < E; ++e) {
            int s = src[e], d = dst[e];
            float w = ew[e];
            int slot = atomicAdd(&cnt[(size_t)d * CSTR], 1);
            if (slot < MAXDEG) ell[d * MAXDEG + slot] = make_uint2((unsigned)s, __float_as_uint(w));
        }
    }
}

// ---------------- deg[i] = sum of raw weights in row i (coalesced, L2-hot) ---
__global__ __launch_bounds__(256) void k_degsum(
    const int* __restrict__ cnt, uint2* __restrict__ ell,
    float* __restrict__ deg, int n)
{
    const int lane = threadIdx.x & 63;
    const int wv   = threadIdx.x >> 6;
    const int i    = blockIdx.x * 4 + wv;
    if (i >= n) return;
    const int m  = min(cnt[(size_t)i * CSTR], MAXDEG);
    const int m8 = min((m + 7) & ~7, MAXDEG);
    const size_t idx = (size_t)i * MAXDEG + lane;
    float w = 0.f;
    if (lane < m) {
        w = __uint_as_float(ell[idx].y);
    } else if (lane < m8) {
        ell[idx] = make_uint2(0u, 0u);   // pad: norm 0 => no-op in k_agg
    }
    #pragma unroll
    for (int off = 32; off > 0; off >>= 1) w += __shfl_xor(w, off);
    if (lane == 0) deg[i] = w;
}

// ---------------- patch norms: ell[i][j].w = dinv[src]*w*dinv[i] -------------
__global__ __launch_bounds__(256) void k_norm(
    const float* __restrict__ deg, const int* __restrict__ cnt,
    uint2* __restrict__ ell, int n)
{
    const int lane = threadIdx.x & 63;
    const int wv   = threadIdx.x >> 6;
    const int i    = blockIdx.x * 4 + wv;
    if (i >= n) return;
    const int m = min(cnt[(size_t)i * CSTR], MAXDEG);
    if (lane >= m) return;
    const float di = rsqrtf(deg[i] + 1.f);
    const size_t idx = (size_t)i * MAXDEG + lane;
    uint2 e = ell[idx];
    const float nm = rsqrtf(deg[e.x] + 1.f) * __uint_as_float(e.y) * di;
    ell[idx] = make_uint2(e.x, __float_as_uint(nm));
}

// ---------------- MFMA GEMM: C[n][128](bf16) = A[n][128] @ W ----------------
template <bool IN_BF16>
__global__ __launch_bounds__(256, 4) void k_gemm(
    const void* __restrict__ Ain, const unsigned short* __restrict__ Wt,
    unsigned short* __restrict__ C, int n)
{
    __shared__ unsigned short Ws[128 * 128];    // 32 KB
    {   // stage Wt: 2048 uint4; swizzle seg^(row&7) in 16B units
        const uint4* Wv = (const uint4*)Wt;
        uint4* Sv = (uint4*)Ws;
        #pragma unroll
        for (int i = threadIdx.x; i < 2048; i += 256) {
            int row = i >> 4, seg = i & 15;
            Sv[row * 16 + (seg ^ (row & 7))] = Wv[i];
        }
    }
    __syncthreads();

    const float*          Af = (const float*)Ain;
    const unsigned short* Ab = (const unsigned short*)Ain;

    const int wid  = threadIdx.x >> 6;          // 0..3
    const int lane = threadIdx.x & 63;
    const int r    = lane & 15;
    const int kg   = lane >> 4;                 // 0..3
    const int m0   = blockIdx.x * 64 + wid * 16;
    const size_t arow = (size_t)min(m0 + r, n - 1) * 128;

    f32x4 acc[8];
    #pragma unroll
    for (int ct = 0; ct < 8; ++ct) acc[ct] = (f32x4){0.f, 0.f, 0.f, 0.f};

    const short8* Ws8 = (const short8*)Ws;

    #pragma unroll
    for (int ks = 0; ks < 4; ++ks) {
        const int k0 = ks * 32 + kg * 8;
        short8 afrag;
        if constexpr (IN_BF16) {
            afrag = *(const short8*)(Ab + arow + k0);
        } else {
            const float4 lo = *(const float4*)(Af + arow + k0);
            const float4 hi = *(const float4*)(Af + arow + k0 + 4);
            union { short8 s; uint4 u; } cvt;
            cvt.u = make_uint4(bf_pack(lo.x, lo.y), bf_pack(lo.z, lo.w),
                               bf_pack(hi.x, hi.y), bf_pack(hi.z, hi.w));
            afrag = cvt.s;
        }
        const int segi = ks * 4 + kg;
        #pragma unroll
        for (int ct = 0; ct < 8; ++ct) {
            const int ncol = ct * 16 + r;
            const short8 bfrag = Ws8[ncol * 16 + (segi ^ (ncol & 7))];
            acc[ct] = __builtin_amdgcn_mfma_f32_16x16x32_bf16(afrag, bfrag, acc[ct], 0, 0, 0);
        }
    }

    #pragma unroll
    for (int ct = 0; ct < 8; ++ct) {
        #pragma unroll
        for (int reg = 0; reg < 4; ++reg) {
            const int row = m0 + kg * 4 + reg;
            if (row < n) C[(size_t)row * 128 + ct * 16 + r] = bf1(acc[ct][reg]);
        }
    }
}

// ---------------- aggregation over bf16 h, f32 accumulate, bf16 out ----------
template <bool RELU>
__global__ __launch_bounds__(256) void k_agg(
    const unsigned short* __restrict__ h, const uint2* __restrict__ ell,
    const int* __restrict__ cnt, const float* __restrict__ deg,
    const float* __restrict__ bias, unsigned* __restrict__ outp, int n)
{
    const int lane = threadIdx.x & 63;
    const int wv   = threadIdx.x >> 6;
    const int i    = blockIdx.x * 4 + wv;
    if (i >= n) return;
    const int f = lane * 2;
    float ax = 0.f, ay = 0.f;
    const int m    = min(cnt[(size_t)i * CSTR], MAXDEG);
    const int m8   = min((m + 7) & ~7, MAXDEG);
    const int base = i * MAXDEG;
    for (int j = 0; j < m8; j += 8) {
        const uint4 p0 = *(const uint4*)&ell[base + j];      // entries j, j+1
        const uint4 p1 = *(const uint4*)&ell[base + j + 2];
        const uint4 p2 = *(const uint4*)&ell[base + j + 4];
        const uint4 p3 = *(const uint4*)&ell[base + j + 6];
        const unsigned g0 = *(const unsigned*)&h[(size_t)p0.x * 128 + f];
        const unsigned g1 = *(const unsigned*)&h[(size_t)p0.z * 128 + f];
        const unsigned g2 = *(const unsigned*)&h[(size_t)p1.x * 128 + f];
        const unsigned g3 = *(const unsigned*)&h[(size_t)p1.z * 128 + f];
        const unsigned g4 = *(const unsigned*)&h[(size_t)p2.x * 128 + f];
        const unsigned g5 = *(const unsigned*)&h[(size_t)p2.z * 128 + f];
        const unsigned g6 = *(const unsigned*)&h[(size_t)p3.x * 128 + f];
        const unsigned g7 = *(const unsigned*)&h[(size_t)p3.z * 128 + f];
        const float w0 = __uint_as_float(p0.y), w1 = __uint_as_float(p0.w);
        const float w2 = __uint_as_float(p1.y), w3 = __uint_as_float(p1.w);
        const float w4 = __uint_as_float(p2.y), w5 = __uint_as_float(p2.w);
        const float w6 = __uint_as_float(p3.y), w7 = __uint_as_float(p3.w);
        ax = fmaf(w0, bf_lo(g0), ax); ay = fmaf(w0, bf_hi(g0), ay);
        ax = fmaf(w1, bf_lo(g1), ax); ay = fmaf(w1, bf_hi(g1), ay);
        ax = fmaf(w2, bf_lo(g2), ax); ay = fmaf(w2, bf_hi(g2), ay);
        ax = fmaf(w3, bf_lo(g3), ax); ay = fmaf(w3, bf_hi(g3), ay);
        ax = fmaf(w4, bf_lo(g4), ax); ay = fmaf(w4, bf_hi(g4), ay);
        ax = fmaf(w5, bf_lo(g5), ax); ay = fmaf(w5, bf_hi(g5), ay);
        ax = fmaf(w6, bf_lo(g6), ax); ay = fmaf(w6, bf_hi(g6), ay);
        ax = fmaf(w7, bf_lo(g7), ax); ay = fmaf(w7, bf_hi(g7), ay);
    }
    const float di = rsqrtf(deg[i] + 1.f);
    const float wl = di * di;
    const unsigned hs = *(const unsigned*)&h[(size_t)i * 128 + f];
    ax = fmaf(wl, bf_lo(hs), ax);
    ay = fmaf(wl, bf_hi(hs), ay);
    const float2 bb = *(const float2*)&bias[f];
    ax += bb.x; ay += bb.y;
    if (RELU) { ax = fmaxf(ax, 0.f); ay = fmaxf(ay, 0.f); }
    outp[(size_t)i * 64 + lane] = bf_pack(ax, ay);
}

// ---------------- mean pool per graph over bf16 h: 1024 threads = 16 waves ---
__global__ __launch_bounds__(1024) void k_pool(
    const unsigned* __restrict__ h, const int* __restrict__ batch,
    float* __restrict__ gout, int n)
{
    const int gi   = blockIdx.x;
    const int lane = threadIdx.x & 63;
    const int wv   = threadIdx.x >> 6;        // 0..15
    __shared__ int sse[2];
    __shared__ float red[16 * 128];
    if (threadIdx.x < 2) {
        const int target = gi + (int)threadIdx.x;
        int lo = 0, hi = n;
        while (lo < hi) { int m = (lo + hi) >> 1; if (batch[m] < target) lo = m + 1; else hi = m; }
        sse[threadIdx.x] = lo;
    }
    __syncthreads();
    const int ss = sse[0], se = sse[1];
    const int f = lane * 2;
    float ax = 0.f, ay = 0.f;
    for (int i = ss + wv; i < se; i += 16) {
        const unsigned hv = h[(size_t)i * 64 + lane];
        ax += bf_lo(hv); ay += bf_hi(hv);
    }
    red[wv * 128 + f]     = ax;
    red[wv * 128 + f + 1] = ay;
    __syncthreads();
    if (threadIdx.x < 128) {
        const int t = threadIdx.x;
        float acc = 0.f;
        #pragma unroll
        for (int j = 0; j < 16; ++j) acc += red[j * 128 + t];
        const float c = (float)(se - ss);
        gout[gi * 128 + t] = acc / fmaxf(c, 1.f);
    }
}

// ---------------- fused head: Linear->ReLU->LayerNorm->Linear ----------------
__global__ __launch_bounds__(128) void k_head(
    const float* __restrict__ g, const float* __restrict__ l1W,
    const float* __restrict__ l1b, const float* __restrict__ gamma,
    const float* __restrict__ beta, const float* __restrict__ l2W,
    const float* __restrict__ l2b, float* __restrict__ out)
{
    const int gi = blockIdx.x;
    const int t  = threadIdx.x;      // 128 threads
    __shared__ float gs[128], zs[128], red[128];
    gs[t] = g[gi * 128 + t];
    __syncthreads();
    float acc = l1b[t];
    for (int k = 0; k < 128; ++k) acc = fmaf(gs[k], l1W[k * 128 + t], acc);
    acc = fmaxf(acc, 0.f);
    red[t] = acc; __syncthreads();
    for (int off = 64; off > 0; off >>= 1) {
        if (t < off) red[t] += red[t + off];
        __syncthreads();
    }
    const float mu = red[0] * (1.f / 128.f);
    __syncthreads();
    const float d = acc - mu;
    red[t] = d * d; __syncthreads();
    for (int off = 64; off > 0; off >>= 1) {
        if (t < off) red[t] += red[t + off];
        __syncthreads();
    }
    const float var = red[0] * (1.f / 128.f);
    const float z = (acc - mu) * rsqrtf(var + 1e-5f) * gamma[t] + beta[t];
    zs[t] = z;
    __syncthreads();
    if (t < 16) {
        float o = l2b[t];
        for (int k = 0; k < 128; ++k) o = fmaf(zs[k], l2W[k * 16 + t], o);
        out[gi * 16 + t] = o;
    }
}

extern "C" void kernel_launch(void* const* d_in, const int* in_sizes, int n_in,
                              void* d_out, int out_size, void* d_ws, size_t ws_size,
                              hipStream_t stream)
{
    const float* x    = (const float*)d_in[0];
    const int*   ei   = (const int*)  d_in[1];
    const float* ew   = (const float*)d_in[2];
    const int*   bidx = (const int*)  d_in[3];
    const float* W1   = (const float*)d_in[4];
    const float* b1   = (const float*)d_in[5];
    const float* W2   = (const float*)d_in[6];
    const float* b2   = (const float*)d_in[7];
    const float* l1W  = (const float*)d_in[8];
    const float* l1b  = (const float*)d_in[9];
    const float* gam  = (const float*)d_in[10];
    const float* bet  = (const float*)d_in[11];
    const float* l2W  = (const float*)d_in[12];
    const float* l2b  = (const float*)d_in[13];
    float* out = (float*)d_out;

    const int E = in_sizes[2];              // edge_weight count
    const int n = in_sizes[3];              // batch_idx count = N nodes
    const int* e_src = ei;                  // edge_index[0]
    const int* e_dst = ei + E;              // edge_index[1]

    char* p = (char*)d_ws;
    auto alloc = [&](size_t bytes) { char* r = p; p += (bytes + 255) & ~(size_t)255; return r; };
    unsigned short* h16_a = (unsigned short*)alloc((size_t)n * 128 * 2);  // gemm out
    unsigned short* h16_b = (unsigned short*)alloc((size_t)n * 128 * 2);  // agg out
    uint2* ell   = (uint2*)alloc((size_t)n * MAXDEG * 8);
    float* deg   = (float*)alloc((size_t)n * 4);
    int*   cnt   = (int*)  alloc((size_t)n * CSTR * 4);                   // 64B/node
    float* gp    = (float*)alloc((size_t)128 * 128 * 4);
    unsigned short* W1t = (unsigned short*)alloc((size_t)128 * 128 * 2);
    unsigned short* W2t = (unsigned short*)alloc((size_t)128 * 128 * 2);

    const int initWork = (n > 16384 ? n : 16384);
    k_init<<<(initWork + 255) / 256, 256, 0, stream>>>(W1, W2, W1t, W2t, cnt, n);

    const int gE8 = (E / 8 + 255) / 256 + 1;
    k_build <<<gE8, 256, 0, stream>>>(e_src, e_dst, ew, cnt, ell, E);
    k_degsum<<<(n + 3) / 4, 256, 0, stream>>>(cnt, ell, deg, n);
    k_norm  <<<(n + 3) / 4, 256, 0, stream>>>(deg, cnt, ell, n);

    const int NB = (n + 63) / 64;           // one 64-row tile per block
    k_gemm<false><<<NB, 256, 0, stream>>>(x,     W1t, h16_a, n);
    k_agg<true> <<<(n + 3) / 4, 256, 0, stream>>>(h16_a, ell, cnt, deg, b1, (unsigned*)h16_b, n);
    k_gemm<true> <<<NB, 256, 0, stream>>>(h16_b, W2t, h16_a, n);
    k_agg<false><<<(n + 3) / 4, 256, 0, stream>>>(h16_a, ell, cnt, deg, b2, (unsigned*)h16_b, n);

    k_pool<<<128, 1024, 0, stream>>>((const unsigned*)h16_b, bidx, gp, n);
    k_head<<<128, 128, 0, stream>>>(gp, l1W, l1b, gam, bet, l2W, l2b, out);
}